// Round 9
// baseline (164.482 us; speedup 1.0000x reference)
//
#include <hip/hip_runtime.h>
#include <stdint.h>

typedef __attribute__((ext_vector_type(8))) __bf16 bf16x8;
typedef __attribute__((ext_vector_type(4))) __bf16 bf16x4;
typedef __attribute__((ext_vector_type(4))) float f32x4;
typedef __attribute__((ext_vector_type(4))) unsigned int u32x4;

#define SEQ 2048
#define LOG2E 1.4426950408889634f

// ---------- ws layout (bytes) ----------
#define OFF_HS2   0ull               // bf16 [8192][1024]  ([hi|lo] along K)
#define OFF_VT    0ull               // bf16 [32][64][2048]   (overlay, after GEMM; k-permuted cols)
#define OFF_AO    8388608ull         // bf16 [8192][512]      (overlay, after GEMM)
#define OFF_WQKV2 16777216ull        // bf16 [1536][1536]  (w_t[n][k'], k'=[hi|hi|lo]; Wq pre-scaled by log2e)
#define OFF_WO    21495808ull        // bf16 [512][512]
#define OFF_QH    22020096ull        // bf16 [32][2048][64]
#define OFF_QL    30408704ull
#define OFF_K     38797312ull
#define OFF_V     47185920ull
#define OFF_BIAS  55574528ull        // f32 [8][4096]  (scaled by log2e)

__device__ __forceinline__ int swz(int row) { return ((row & 7) << 4) ^ ((row & 8) << 1); }

__device__ __forceinline__ void gl_lds16(const void* g, void* l) {
  __builtin_amdgcn_global_load_lds(
      (__attribute__((address_space(1))) void*)(uintptr_t)g,
      (__attribute__((address_space(3))) void*)(uint32_t)(uintptr_t)l, 16, 0, 0);
}

// ---------- prep: hidden_states f32 -> [hi|lo] bf16, K' = 1024 (read once) ----------
__global__ void k_cast_hs2(const float* __restrict__ hs, __bf16* __restrict__ out) {
  int gid = blockIdx.x * 256 + threadIdx.x;       // 524288
  int row = gid >> 6, c8 = (gid & 63) * 8;
  const float* p = hs + (size_t)row * 512 + c8;
  float4 a = *(const float4*)p, b = *(const float4*)(p + 4);
  float v[8] = {a.x, a.y, a.z, a.w, b.x, b.y, b.z, b.w};
  bf16x8 hi, lo;
#pragma unroll
  for (int j = 0; j < 8; ++j) {
    __bf16 h = (__bf16)v[j];
    hi[j] = h;
    lo[j] = (__bf16)(v[j] - (float)h);
  }
  *(bf16x8*)(out + (size_t)row * 1024 + c8) = hi;
  *(bf16x8*)(out + (size_t)row * 1024 + 512 + c8) = lo;
}

// ---------- prep: QKV weights -> transposed split [1536][1536]; Wq scaled by log2e ----------
__global__ void k_prep_w2(const float* __restrict__ Wq, const float* __restrict__ Wk,
                          const float* __restrict__ Wv, __bf16* __restrict__ w2) {
  __shared__ float tile[64][65];
  int z = blockIdx.z;
  const float* W = (z == 0) ? Wq : (z == 1) ? Wk : Wv;
  float scale = (z == 0) ? LOG2E : 1.0f;
  int k0 = blockIdx.y * 64, n0 = blockIdx.x * 64;
  int tx = threadIdx.x & 63, ty = threadIdx.x >> 6;
  for (int r = ty; r < 64; r += 4) tile[r][tx] = W[(size_t)(k0 + r) * 512 + n0 + tx];
  __syncthreads();
  for (int r = ty; r < 64; r += 4) {
    float v = tile[tx][r] * scale;               // (k=k0+tx, n=n0+r)
    __bf16 h = (__bf16)v;
    __bf16 lo = (__bf16)(v - (float)h);
    __bf16* dst = w2 + (size_t)(z * 512 + n0 + r) * 1536;
    dst[k0 + tx] = h;
    dst[512 + k0 + tx] = h;
    dst[1024 + k0 + tx] = lo;
  }
}

__global__ void k_prep_wo(const float* __restrict__ Wo, __bf16* __restrict__ wo_t) {
  int idx = blockIdx.x * 256 + threadIdx.x;
  int n = idx >> 9, k = idx & 511;
  wo_t[idx] = (__bf16)Wo[(size_t)k * 512 + n];
}

// ---------- prep: T5 relative-position bias table (log2e-scaled) ----------
__global__ void k_bias(const float* __restrict__ rel_bias, float* __restrict__ bias_tab) {
  int idx = blockIdx.x * 256 + threadIdx.x;
  int h = idx >> 12, dIdx = idx & 4095;
  float v = 0.f;
  if (dIdx < 4095) {
    int d = dIdx - 2047;
    int rp = d < 0 ? -d : d;
    int bp;
    if (rp < 8) bp = rp;
    else bp = 8 + (rp >= 12) + (rp >= 16) + (rp >= 23) + (rp >= 32) + (rp >= 46) + (rp >= 64) + (rp >= 91);
    v = rel_bias[((d > 0 ? 16 : 0) + bp) * 8 + h] * LOG2E;
  }
  bias_tab[idx] = v;
}

// ---------- GEMM; MODE 0: QKV split (V-blocks run 16 K-steps, Q/K 48) ----------
template <int MODE, int KSTEPS, int LDA, int LDB>
__global__ __launch_bounds__(256) void k_gemm(const __bf16* __restrict__ A,
                                              const __bf16* __restrict__ Bt,
                                              __bf16* __restrict__ qh, __bf16* __restrict__ ql,
                                              __bf16* __restrict__ ko, __bf16* __restrict__ vo,
                                              float* __restrict__ fo) {
  __shared__ __align__(16) __bf16 As[2][128 * 32];
  __shared__ __align__(16) __bf16 Bs[2][128 * 32];
  int tid = threadIdx.x, w = tid >> 6, l = tid & 63;
  int lr = l & 15, lh = l >> 4;
  int m0 = blockIdx.y * 128, n0 = blockIdx.x * 128;
  int wm = (w >> 1) * 64, wn = (w & 1) * 64;
  int ksteps = (MODE == 0 && n0 >= 1024) ? 16 : KSTEPS;  // V: plain hi*hi only
  f32x4 zero4 = {0.f, 0.f, 0.f, 0.f};
  f32x4 acc[4][4];
#pragma unroll
  for (int i = 0; i < 4; ++i)
#pragma unroll
    for (int j = 0; j < 4; ++j) acc[i][j] = zero4;

  auto stage = [&](int kt, int buf) {
    int ka = (MODE == 0 && kt >= 32) ? kt - 32 : kt;
#pragma unroll
    for (int c = 0; c < 2; ++c) {
      int i = c * 256 + w * 64 + l;
      int row = i >> 2, cc = i & 3;
      gl_lds16(A + (size_t)(m0 + row) * LDA + ka * 32 + cc * 8,
               (char*)&As[buf][0] + (c * 256 + w * 64) * 16);
      gl_lds16(Bt + (size_t)(n0 + row) * LDB + kt * 32 + cc * 8,
               (char*)&Bs[buf][0] + (c * 256 + w * 64) * 16);
    }
  };

  stage(0, 0);
  __syncthreads();
  int cur = 0;
  for (int kt = 0; kt < ksteps; ++kt) {
    if (kt + 1 < ksteps) stage(kt + 1, cur ^ 1);
    bf16x8 af[4], bfr[4];
#pragma unroll
    for (int mi = 0; mi < 4; ++mi)
      af[mi] = *(const bf16x8*)&As[cur][(wm + mi * 16 + lr) * 32 + lh * 8];
#pragma unroll
    for (int ni = 0; ni < 4; ++ni)
      bfr[ni] = *(const bf16x8*)&Bs[cur][(wn + ni * 16 + lr) * 32 + lh * 8];
#pragma unroll
    for (int mi = 0; mi < 4; ++mi)
#pragma unroll
      for (int ni = 0; ni < 4; ++ni)
        acc[mi][ni] = __builtin_amdgcn_mfma_f32_16x16x32_bf16(af[mi], bfr[ni], acc[mi][ni], 0, 0, 0);
    __syncthreads();
    cur ^= 1;
  }

#pragma unroll
  for (int mi = 0; mi < 4; ++mi)
#pragma unroll
    for (int ni = 0; ni < 4; ++ni)
#pragma unroll
      for (int r = 0; r < 4; ++r) {
        int m = m0 + wm + mi * 16 + lh * 4 + r;
        int n = n0 + wn + ni * 16 + lr;
        float vv = acc[mi][ni][r];
        if (MODE == 0) {
          int which = n >> 9, c9 = n & 511, hh = c9 >> 6, dh = c9 & 63;
          int b = m >> 11, s = m & 2047;
          size_t o = (size_t)((b * 8 + hh) * 2048 + s) * 64 + dh;
          if (which == 0) {
            __bf16 hv = (__bf16)vv;
            qh[o] = hv;
            ql[o] = (__bf16)(vv - (float)hv);
          } else if (which == 1) {
            ko[o] = (__bf16)vv;
          } else {
            vo[o] = (__bf16)vv;
          }
        } else {
          fo[(size_t)m * 512 + n] = vv;
        }
      }
}

// ---------- transpose V to [bh][dh][s], with per-64 k-column permutation ----------
// dest 4-col group d2 for source group c2:  k = 32a+16u+4m+v  ->  p = 32a+8m+4u+v
__global__ void k_transv(const __bf16* __restrict__ v, __bf16* __restrict__ vt) {
  __shared__ __bf16 t[64][72];
  int bh = blockIdx.y, s0 = blockIdx.x * 64, tid = threadIdx.x;
  const __bf16* src = v + (size_t)bh * SEQ * 64;
  __bf16* dst = vt + (size_t)bh * 64 * SEQ;
#pragma unroll
  for (int c = 0; c < 2; ++c) {
    int i = c * 256 + tid, row = i >> 3, col = (i & 7) * 8;
    *(bf16x8*)&t[row][col] = *(const bf16x8*)&src[(size_t)(s0 + row) * 64 + col];
  }
  __syncthreads();
#pragma unroll
  for (int c = 0; c < 2; ++c) {
    int i = c * 256 + tid, dh = i >> 3, c8 = i & 7;
    bf16x4 o1, o2;
#pragma unroll
    for (int j = 0; j < 4; ++j) { o1[j] = t[c8 * 8 + j][dh]; o2[j] = t[c8 * 8 + 4 + j][dh]; }
    int c2a = 2 * c8, c2b = 2 * c8 + 1;
    int d2a = ((c2a >> 3) << 3) | ((c2a & 3) << 1) | ((c2a >> 2) & 1);
    int d2b = ((c2b >> 3) << 3) | ((c2b & 3) << 1) | ((c2b >> 2) & 1);
    *(bf16x4*)&dst[(size_t)dh * SEQ + s0 + 4 * d2a] = o1;
    *(bf16x4*)&dst[(size_t)dh * SEQ + s0 + 4 * d2b] = o2;
  }
}

// ---------- flash attention: swapped QK^T, register P (k-permuted PV), exp2 domain ----------
__global__ __launch_bounds__(512) void k_attn(const __bf16* __restrict__ qhp,
                                              const __bf16* __restrict__ qlp,
                                              const __bf16* __restrict__ k,
                                              const __bf16* __restrict__ vt,
                                              const float* __restrict__ bias_tab,
                                              __bf16* __restrict__ ao) {
  __shared__ __align__(16) __bf16 Ks[2][64 * 64];
  __shared__ __align__(16) __bf16 Vs[2][64 * 64];
  __shared__ __align__(16) __bf16 Qs[128 * 64];   // Q staging only
  __shared__ float bias_s[2176];
  int tid = threadIdx.x, w = tid >> 6, l = tid & 63;
  int lr = l & 15, lh = l >> 4;
  int d = blockIdx.x;
  int bh = (d & 7) + ((d >> 3) & 3) * 8;
  int q0 = (d >> 5) * 128;
  int h = bh & 7, b = bh >> 3;
  const char* kbase = (const char*)(k + (size_t)bh * SEQ * 64);
  const char* vbase = (const char*)(vt + (size_t)bh * 64 * SEQ);

  for (int j = tid; j < 2176; j += 512)
    bias_s[j] = bias_tab[h * 4096 + (1920 - q0) + j];

  auto stageKV = [&](int kt, int buf) {
    const char* kb = kbase + (size_t)kt * 64 * 128;
    const char* vb = vbase + (size_t)kt * 128;
    int row = tid >> 3, colb = (tid & 7) * 16;
    gl_lds16(kb + row * 128 + (colb ^ swz(row)), (char*)&Ks[buf][0] + tid * 16);
    gl_lds16(vb + (size_t)row * 4096 + (colb ^ swz(row)), (char*)&Vs[buf][0] + tid * 16);
  };

  auto stageQ = [&](const __bf16* qsrc) {
    const char* qb = (const char*)(qsrc + (size_t)bh * SEQ * 64) + (size_t)q0 * 128;
#pragma unroll
    for (int c = 0; c < 2; ++c) {
      int i = c * 512 + tid;
      int row = i >> 3, colb = (i & 7) * 16;
      gl_lds16(qb + row * 128 + (colb ^ swz(row)), (char*)&Qs[0] + i * 16);
    }
  };

  bf16x8 qfh[2], qfl[2];
  int qrow = w * 16 + lr;
  const char* qread = (const char*)&Qs[0];

  stageQ(qhp);
  __syncthreads();
  qfh[0] = *(const bf16x8*)(qread + qrow * 128 + ((lh * 16) ^ swz(qrow)));
  qfh[1] = *(const bf16x8*)(qread + qrow * 128 + ((64 + lh * 16) ^ swz(qrow)));
  __syncthreads();
  stageQ(qlp);
  stageKV(0, 0);
  __syncthreads();
  qfl[0] = *(const bf16x8*)(qread + qrow * 128 + ((lh * 16) ^ swz(qrow)));
  qfl[1] = *(const bf16x8*)(qread + qrow * 128 + ((64 + lh * 16) ^ swz(qrow)));

  float m_run = -1e30f, l_run = 0.f;
  f32x4 zero4 = {0.f, 0.f, 0.f, 0.f};
  f32x4 oacc[4];
#pragma unroll
  for (int i = 0; i < 4; ++i) oacc[i] = zero4;

#pragma unroll 2
  for (int kt = 0; kt < 32; ++kt) {
    int cur = kt & 1;
    if (kt + 1 < 32) stageKV(kt + 1, cur ^ 1);
    const char* kb = (const char*)&Ks[cur][0];
    f32x4 sacc[4];
    __builtin_amdgcn_s_setprio(1);
#pragma unroll
    for (int t = 0; t < 4; ++t) {
      int row = t * 16 + lr;
      bf16x8 b0 = *(const bf16x8*)(kb + row * 128 + ((lh * 16) ^ swz(row)));
      bf16x8 b1 = *(const bf16x8*)(kb + row * 128 + ((64 + lh * 16) ^ swz(row)));
      f32x4 z = zero4;
      z = __builtin_amdgcn_mfma_f32_16x16x32_bf16(b0, qfh[0], z, 0, 0, 0);
      z = __builtin_amdgcn_mfma_f32_16x16x32_bf16(b1, qfh[1], z, 0, 0, 0);
      z = __builtin_amdgcn_mfma_f32_16x16x32_bf16(b0, qfl[0], z, 0, 0, 0);
      z = __builtin_amdgcn_mfma_f32_16x16x32_bf16(b1, qfl[1], z, 0, 0, 0);
      sacc[t] = z;
    }
    __builtin_amdgcn_s_setprio(0);
    // lane (lr,lh) reg (t,r): S[q = q0+w*16+lr][k = kt*64 + t*16 + lh*4 + r]  (log2 domain)
    float p[4][4];
    int jb = kt * 64 + lh * 4 + 127 - (w * 16 + lr);
    float mx = -1e30f;
#pragma unroll
    for (int t = 0; t < 4; ++t)
#pragma unroll
      for (int r = 0; r < 4; ++r) {
        float sv = sacc[t][r] + bias_s[jb + t * 16 + r];
        p[t][r] = sv;
        mx = fmaxf(mx, sv);
      }
    mx = fmaxf(mx, __shfl_xor(mx, 16));
    mx = fmaxf(mx, __shfl_xor(mx, 32));
    if (!__all(mx <= m_run + 11.5f)) {             // defer-max (2^11.5 ~ e^8)
      float mnew = fmaxf(m_run, mx);
      float sc = __builtin_exp2f(m_run - mnew);
      m_run = mnew;
      l_run *= sc;
#pragma unroll
      for (int r = 0; r < 4; ++r) {
        float scr = __shfl(sc, lh * 4 + r);        // sc of output row lh*4+r
#pragma unroll
        for (int ni = 0; ni < 4; ++ni) oacc[ni][r] *= scr;
      }
    }
    float rs = 0.f;
#pragma unroll
    for (int t = 0; t < 4; ++t)
#pragma unroll
      for (int r = 0; r < 4; ++r) {
        float pv = __builtin_exp2f(p[t][r] - m_run);
        p[t][r] = pv;
        rs += pv;
      }
    rs += __shfl_xor(rs, 16);
    rs += __shfl_xor(rs, 32);
    l_run += rs;
    // pack P in-register: pa0 slot(lh,e) holds k=16*(e/4)+4*lh+(e&3); V cols permuted to match
    uint32_t pk[4][2];
#pragma unroll
    for (int t = 0; t < 4; ++t) {
      asm("v_cvt_pk_bf16_f32 %0, %1, %2" : "=v"(pk[t][0]) : "v"(p[t][0]), "v"(p[t][1]));
      asm("v_cvt_pk_bf16_f32 %0, %1, %2" : "=v"(pk[t][1]) : "v"(p[t][2]), "v"(p[t][3]));
    }
    u32x4 A0 = {pk[0][0], pk[0][1], pk[1][0], pk[1][1]};
    u32x4 A1 = {pk[2][0], pk[2][1], pk[3][0], pk[3][1]};
    bf16x8 pa0 = __builtin_bit_cast(bf16x8, A0);
    bf16x8 pa1 = __builtin_bit_cast(bf16x8, A1);
    // PV
    {
      const char* vbr = (const char*)&Vs[cur][0];
      __builtin_amdgcn_s_setprio(1);
#pragma unroll
      for (int ni = 0; ni < 4; ++ni) {
        int vrow = ni * 16 + lr;
        bf16x8 v0 = *(const bf16x8*)(vbr + vrow * 128 + ((lh * 16) ^ swz(vrow)));
        bf16x8 v1 = *(const bf16x8*)(vbr + vrow * 128 + ((64 + lh * 16) ^ swz(vrow)));
        oacc[ni] = __builtin_amdgcn_mfma_f32_16x16x32_bf16(pa0, v0, oacc[ni], 0, 0, 0);
        oacc[ni] = __builtin_amdgcn_mfma_f32_16x16x32_bf16(pa1, v1, oacc[ni], 0, 0, 0);
      }
      __builtin_amdgcn_s_setprio(0);
    }
    __syncthreads();
  }

#pragma unroll
  for (int r = 0; r < 4; ++r) {
    float linv = 1.0f / __shfl(l_run, lh * 4 + r);
    int s = q0 + w * 16 + lh * 4 + r;
#pragma unroll
    for (int ni = 0; ni < 4; ++ni) {
      int dh = ni * 16 + lr;
      ao[((size_t)(b * 2048 + s)) * 512 + h * 64 + dh] = (__bf16)(oacc[ni][r] * linv);
    }
  }
}

extern "C" void kernel_launch(void* const* d_in, const int* in_sizes, int n_in,
                              void* d_out, int out_size, void* d_ws, size_t ws_size,
                              hipStream_t stream) {
  (void)in_sizes; (void)n_in; (void)out_size; (void)ws_size;
  const float* hs = (const float*)d_in[0];
  const float* Wq = (const float*)d_in[1];
  const float* Wk = (const float*)d_in[2];
  const float* Wv = (const float*)d_in[3];
  const float* Wo = (const float*)d_in[4];
  const float* rb = (const float*)d_in[5];
  char* ws = (char*)d_ws;
  __bf16* hs2    = (__bf16*)(ws + OFF_HS2);
  __bf16* wqkv2  = (__bf16*)(ws + OFF_WQKV2);
  __bf16* wo_t   = (__bf16*)(ws + OFF_WO);
  __bf16* qhb    = (__bf16*)(ws + OFF_QH);
  __bf16* qlb    = (__bf16*)(ws + OFF_QL);
  __bf16* kb     = (__bf16*)(ws + OFF_K);
  __bf16* vb     = (__bf16*)(ws + OFF_V);
  __bf16* vtb    = (__bf16*)(ws + OFF_VT);
  __bf16* aob    = (__bf16*)(ws + OFF_AO);
  float*  bias   = (float*)(ws + OFF_BIAS);

  k_cast_hs2<<<2048, 256, 0, stream>>>(hs, hs2);
  k_prep_w2<<<dim3(8, 8, 3), 256, 0, stream>>>(Wq, Wk, Wv, wqkv2);
  k_prep_wo<<<1024, 256, 0, stream>>>(Wo, wo_t);
  k_bias<<<128, 256, 0, stream>>>(rb, bias);
  k_gemm<0, 48, 1024, 1536><<<dim3(12, 64), 256, 0, stream>>>(hs2, wqkv2, qhb, qlb, kb, vb, nullptr);
  k_transv<<<dim3(32, 32), 256, 0, stream>>>(vb, vtb);
  k_attn<<<dim3(512), 512, 0, stream>>>(qhb, qlb, kb, vtb, bias, aob);
  k_gemm<1, 16, 512, 512><<<dim3(4, 64), 256, 0, stream>>>(aob, wo_t, nullptr, nullptr, nullptr, nullptr, (float*)d_out);
}

// Round 10
// 152.616 us; speedup vs baseline: 1.0777x; 1.0777x over previous
//
#include <hip/hip_runtime.h>
#include <stdint.h>

typedef __attribute__((ext_vector_type(8))) __bf16 bf16x8;
typedef __attribute__((ext_vector_type(4))) __bf16 bf16x4;
typedef __attribute__((ext_vector_type(4))) float f32x4;
typedef __attribute__((ext_vector_type(4))) unsigned int u32x4;

#define SEQ 2048
#define LOG2E 1.4426950408889634f

// ---------- ws layout (bytes) ----------
#define OFF_HS2   0ull               // bf16 [8192][1024]  ([hi|lo] along K)
#define OFF_VT    0ull               // bf16 [32][64][2048]   (overlay, after GEMM; k-permuted cols)
#define OFF_AO    8388608ull         // bf16 [8192][512]      (overlay, after GEMM)
#define OFF_WQKV2 16777216ull        // bf16 [1536][1536]  (w_t[n][k'], k'=[hi|hi|lo]; Wq pre-scaled by log2e)
#define OFF_WO    21495808ull        // bf16 [512][512]
#define OFF_QH    22020096ull        // bf16 [32][2048][64]
#define OFF_QL    30408704ull
#define OFF_K     38797312ull
#define OFF_V     47185920ull
#define OFF_BIAS  55574528ull        // f32 [8][4096]  (scaled by log2e)

__device__ __forceinline__ int swz(int row) { return ((row & 7) << 4) ^ ((row & 8) << 1); }

__device__ __forceinline__ void gl_lds16(const void* g, void* l) {
  __builtin_amdgcn_global_load_lds(
      (__attribute__((address_space(1))) void*)(uintptr_t)g,
      (__attribute__((address_space(3))) void*)(uint32_t)(uintptr_t)l, 16, 0, 0);
}

// raw v_exp_f32 (2^x), 1-ulp hardware transcendental — same unit __expf uses
__device__ __forceinline__ float fast_exp2(float x) { return __builtin_amdgcn_exp2f(x); }

// ---------- prep: hidden_states f32 -> [hi|lo] bf16, K' = 1024 (read once) ----------
__global__ void k_cast_hs2(const float* __restrict__ hs, __bf16* __restrict__ out) {
  int gid = blockIdx.x * 256 + threadIdx.x;       // 524288
  int row = gid >> 6, c8 = (gid & 63) * 8;
  const float* p = hs + (size_t)row * 512 + c8;
  float4 a = *(const float4*)p, b = *(const float4*)(p + 4);
  float v[8] = {a.x, a.y, a.z, a.w, b.x, b.y, b.z, b.w};
  bf16x8 hi, lo;
#pragma unroll
  for (int j = 0; j < 8; ++j) {
    __bf16 h = (__bf16)v[j];
    hi[j] = h;
    lo[j] = (__bf16)(v[j] - (float)h);
  }
  *(bf16x8*)(out + (size_t)row * 1024 + c8) = hi;
  *(bf16x8*)(out + (size_t)row * 1024 + 512 + c8) = lo;
}

// ---------- prep: QKV weights -> transposed split [1536][1536]; Wq scaled by log2e ----------
__global__ void k_prep_w2(const float* __restrict__ Wq, const float* __restrict__ Wk,
                          const float* __restrict__ Wv, __bf16* __restrict__ w2) {
  __shared__ float tile[64][65];
  int z = blockIdx.z;
  const float* W = (z == 0) ? Wq : (z == 1) ? Wk : Wv;
  float scale = (z == 0) ? LOG2E : 1.0f;
  int k0 = blockIdx.y * 64, n0 = blockIdx.x * 64;
  int tx = threadIdx.x & 63, ty = threadIdx.x >> 6;
  for (int r = ty; r < 64; r += 4) tile[r][tx] = W[(size_t)(k0 + r) * 512 + n0 + tx];
  __syncthreads();
  for (int r = ty; r < 64; r += 4) {
    float v = tile[tx][r] * scale;               // (k=k0+tx, n=n0+r)
    __bf16 h = (__bf16)v;
    __bf16 lo = (__bf16)(v - (float)h);
    __bf16* dst = w2 + (size_t)(z * 512 + n0 + r) * 1536;
    dst[k0 + tx] = h;
    dst[512 + k0 + tx] = h;
    dst[1024 + k0 + tx] = lo;
  }
}

__global__ void k_prep_wo(const float* __restrict__ Wo, __bf16* __restrict__ wo_t) {
  int idx = blockIdx.x * 256 + threadIdx.x;
  int n = idx >> 9, k = idx & 511;
  wo_t[idx] = (__bf16)Wo[(size_t)k * 512 + n];
}

// ---------- prep: T5 relative-position bias table (log2e-scaled) ----------
__global__ void k_bias(const float* __restrict__ rel_bias, float* __restrict__ bias_tab) {
  int idx = blockIdx.x * 256 + threadIdx.x;
  int h = idx >> 12, dIdx = idx & 4095;
  float v = 0.f;
  if (dIdx < 4095) {
    int d = dIdx - 2047;
    int rp = d < 0 ? -d : d;
    int bp;
    if (rp < 8) bp = rp;
    else bp = 8 + (rp >= 12) + (rp >= 16) + (rp >= 23) + (rp >= 32) + (rp >= 46) + (rp >= 64) + (rp >= 91);
    v = rel_bias[((d > 0 ? 16 : 0) + bp) * 8 + h] * LOG2E;
  }
  bias_tab[idx] = v;
}

// ---------- GEMM; MODE 0: QKV split (V-blocks run 16 K-steps, Q/K 48) ----------
template <int MODE, int KSTEPS, int LDA, int LDB>
__global__ __launch_bounds__(256) void k_gemm(const __bf16* __restrict__ A,
                                              const __bf16* __restrict__ Bt,
                                              __bf16* __restrict__ qh, __bf16* __restrict__ ql,
                                              __bf16* __restrict__ ko, __bf16* __restrict__ vo,
                                              float* __restrict__ fo) {
  __shared__ __align__(16) __bf16 As[2][128 * 32];
  __shared__ __align__(16) __bf16 Bs[2][128 * 32];
  int tid = threadIdx.x, w = tid >> 6, l = tid & 63;
  int lr = l & 15, lh = l >> 4;
  int m0 = blockIdx.y * 128, n0 = blockIdx.x * 128;
  int wm = (w >> 1) * 64, wn = (w & 1) * 64;
  int ksteps = (MODE == 0 && n0 >= 1024) ? 16 : KSTEPS;  // V: plain hi*hi only
  f32x4 zero4 = {0.f, 0.f, 0.f, 0.f};
  f32x4 acc[4][4];
#pragma unroll
  for (int i = 0; i < 4; ++i)
#pragma unroll
    for (int j = 0; j < 4; ++j) acc[i][j] = zero4;

  auto stage = [&](int kt, int buf) {
    int ka = (MODE == 0 && kt >= 32) ? kt - 32 : kt;
#pragma unroll
    for (int c = 0; c < 2; ++c) {
      int i = c * 256 + w * 64 + l;
      int row = i >> 2, cc = i & 3;
      gl_lds16(A + (size_t)(m0 + row) * LDA + ka * 32 + cc * 8,
               (char*)&As[buf][0] + (c * 256 + w * 64) * 16);
      gl_lds16(Bt + (size_t)(n0 + row) * LDB + kt * 32 + cc * 8,
               (char*)&Bs[buf][0] + (c * 256 + w * 64) * 16);
    }
  };

  stage(0, 0);
  __syncthreads();
  int cur = 0;
  for (int kt = 0; kt < ksteps; ++kt) {
    if (kt + 1 < ksteps) stage(kt + 1, cur ^ 1);
    bf16x8 af[4], bfr[4];
#pragma unroll
    for (int mi = 0; mi < 4; ++mi)
      af[mi] = *(const bf16x8*)&As[cur][(wm + mi * 16 + lr) * 32 + lh * 8];
#pragma unroll
    for (int ni = 0; ni < 4; ++ni)
      bfr[ni] = *(const bf16x8*)&Bs[cur][(wn + ni * 16 + lr) * 32 + lh * 8];
#pragma unroll
    for (int mi = 0; mi < 4; ++mi)
#pragma unroll
      for (int ni = 0; ni < 4; ++ni)
        acc[mi][ni] = __builtin_amdgcn_mfma_f32_16x16x32_bf16(af[mi], bfr[ni], acc[mi][ni], 0, 0, 0);
    __syncthreads();
    cur ^= 1;
  }

#pragma unroll
  for (int mi = 0; mi < 4; ++mi)
#pragma unroll
    for (int ni = 0; ni < 4; ++ni)
#pragma unroll
      for (int r = 0; r < 4; ++r) {
        int m = m0 + wm + mi * 16 + lh * 4 + r;
        int n = n0 + wn + ni * 16 + lr;
        float vv = acc[mi][ni][r];
        if (MODE == 0) {
          int which = n >> 9, c9 = n & 511, hh = c9 >> 6, dh = c9 & 63;
          int b = m >> 11, s = m & 2047;
          size_t o = (size_t)((b * 8 + hh) * 2048 + s) * 64 + dh;
          if (which == 0) {
            __bf16 hv = (__bf16)vv;
            qh[o] = hv;
            ql[o] = (__bf16)(vv - (float)hv);
          } else if (which == 1) {
            ko[o] = (__bf16)vv;
          } else {
            vo[o] = (__bf16)vv;
          }
        } else {
          fo[(size_t)m * 512 + n] = vv;
        }
      }
}

// ---------- transpose V to [bh][dh][s], with per-64 k-column permutation ----------
// dest 4-col group d2 for source group c2:  k = 32a+16u+4m+v  ->  p = 32a+8m+4u+v
__global__ void k_transv(const __bf16* __restrict__ v, __bf16* __restrict__ vt) {
  __shared__ __bf16 t[64][72];
  int bh = blockIdx.y, s0 = blockIdx.x * 64, tid = threadIdx.x;
  const __bf16* src = v + (size_t)bh * SEQ * 64;
  __bf16* dst = vt + (size_t)bh * 64 * SEQ;
#pragma unroll
  for (int c = 0; c < 2; ++c) {
    int i = c * 256 + tid, row = i >> 3, col = (i & 7) * 8;
    *(bf16x8*)&t[row][col] = *(const bf16x8*)&src[(size_t)(s0 + row) * 64 + col];
  }
  __syncthreads();
#pragma unroll
  for (int c = 0; c < 2; ++c) {
    int i = c * 256 + tid, dh = i >> 3, c8 = i & 7;
    bf16x4 o1, o2;
#pragma unroll
    for (int j = 0; j < 4; ++j) { o1[j] = t[c8 * 8 + j][dh]; o2[j] = t[c8 * 8 + 4 + j][dh]; }
    int c2a = 2 * c8, c2b = 2 * c8 + 1;
    int d2a = ((c2a >> 3) << 3) | ((c2a & 3) << 1) | ((c2a >> 2) & 1);
    int d2b = ((c2b >> 3) << 3) | ((c2b & 3) << 1) | ((c2b >> 2) & 1);
    *(bf16x4*)&dst[(size_t)dh * SEQ + s0 + 4 * d2a] = o1;
    *(bf16x4*)&dst[(size_t)dh * SEQ + s0 + 4 * d2b] = o2;
  }
}

// ---------- flash attention: swapped QK^T, register P (k-permuted PV), exp2 domain ----------
__global__ __launch_bounds__(512) void k_attn(const __bf16* __restrict__ qhp,
                                              const __bf16* __restrict__ qlp,
                                              const __bf16* __restrict__ k,
                                              const __bf16* __restrict__ vt,
                                              const float* __restrict__ bias_tab,
                                              __bf16* __restrict__ ao) {
  __shared__ __align__(16) __bf16 Ks[2][64 * 64];
  __shared__ __align__(16) __bf16 Vs[2][64 * 64];
  __shared__ __align__(16) __bf16 Qs[128 * 64];   // Q staging only
  __shared__ float bias_s[2176];
  int tid = threadIdx.x, w = tid >> 6, l = tid & 63;
  int lr = l & 15, lh = l >> 4;
  int d = blockIdx.x;
  int bh = (d & 7) + ((d >> 3) & 3) * 8;
  int q0 = (d >> 5) * 128;
  int h = bh & 7, b = bh >> 3;
  const char* kbase = (const char*)(k + (size_t)bh * SEQ * 64);
  const char* vbase = (const char*)(vt + (size_t)bh * 64 * SEQ);

  for (int j = tid; j < 2176; j += 512)
    bias_s[j] = bias_tab[h * 4096 + (1920 - q0) + j];

  auto stageKV = [&](int kt, int buf) {
    const char* kb = kbase + (size_t)kt * 64 * 128;
    const char* vb = vbase + (size_t)kt * 128;
    int row = tid >> 3, colb = (tid & 7) * 16;
    gl_lds16(kb + row * 128 + (colb ^ swz(row)), (char*)&Ks[buf][0] + tid * 16);
    gl_lds16(vb + (size_t)row * 4096 + (colb ^ swz(row)), (char*)&Vs[buf][0] + tid * 16);
  };

  auto stageQ = [&](const __bf16* qsrc) {
    const char* qb = (const char*)(qsrc + (size_t)bh * SEQ * 64) + (size_t)q0 * 128;
#pragma unroll
    for (int c = 0; c < 2; ++c) {
      int i = c * 512 + tid;
      int row = i >> 3, colb = (i & 7) * 16;
      gl_lds16(qb + row * 128 + (colb ^ swz(row)), (char*)&Qs[0] + i * 16);
    }
  };

  bf16x8 qfh[2], qfl[2];
  int qrow = w * 16 + lr;
  const char* qread = (const char*)&Qs[0];

  stageQ(qhp);
  __syncthreads();
  qfh[0] = *(const bf16x8*)(qread + qrow * 128 + ((lh * 16) ^ swz(qrow)));
  qfh[1] = *(const bf16x8*)(qread + qrow * 128 + ((64 + lh * 16) ^ swz(qrow)));
  __syncthreads();
  stageQ(qlp);
  stageKV(0, 0);
  __syncthreads();
  qfl[0] = *(const bf16x8*)(qread + qrow * 128 + ((lh * 16) ^ swz(qrow)));
  qfl[1] = *(const bf16x8*)(qread + qrow * 128 + ((64 + lh * 16) ^ swz(qrow)));

  float m_run = -1e30f, l_run = 0.f;
  f32x4 zero4 = {0.f, 0.f, 0.f, 0.f};
  f32x4 oacc[4];
#pragma unroll
  for (int i = 0; i < 4; ++i) oacc[i] = zero4;

#pragma unroll 2
  for (int kt = 0; kt < 32; ++kt) {
    int cur = kt & 1;
    if (kt + 1 < 32) stageKV(kt + 1, cur ^ 1);
    const char* kb = (const char*)&Ks[cur][0];
    f32x4 sacc[4];
    __builtin_amdgcn_s_setprio(1);
#pragma unroll
    for (int t = 0; t < 4; ++t) {
      int row = t * 16 + lr;
      bf16x8 b0 = *(const bf16x8*)(kb + row * 128 + ((lh * 16) ^ swz(row)));
      bf16x8 b1 = *(const bf16x8*)(kb + row * 128 + ((64 + lh * 16) ^ swz(row)));
      f32x4 z = zero4;
      z = __builtin_amdgcn_mfma_f32_16x16x32_bf16(b0, qfh[0], z, 0, 0, 0);
      z = __builtin_amdgcn_mfma_f32_16x16x32_bf16(b1, qfh[1], z, 0, 0, 0);
      z = __builtin_amdgcn_mfma_f32_16x16x32_bf16(b0, qfl[0], z, 0, 0, 0);
      z = __builtin_amdgcn_mfma_f32_16x16x32_bf16(b1, qfl[1], z, 0, 0, 0);
      sacc[t] = z;
    }
    __builtin_amdgcn_s_setprio(0);
    // lane (lr,lh) reg (t,r): S[q = q0+w*16+lr][k = kt*64 + t*16 + lh*4 + r]  (log2 domain)
    float p[4][4];
    int jb = kt * 64 + lh * 4 + 127 - (w * 16 + lr);
    float mx = -1e30f;
#pragma unroll
    for (int t = 0; t < 4; ++t)
#pragma unroll
      for (int r = 0; r < 4; ++r) {
        float sv = sacc[t][r] + bias_s[jb + t * 16 + r];
        p[t][r] = sv;
        mx = fmaxf(mx, sv);
      }
    mx = fmaxf(mx, __shfl_xor(mx, 16));
    mx = fmaxf(mx, __shfl_xor(mx, 32));
    if (!__all(mx <= m_run + 11.5f)) {             // defer-max (2^11.5 ~ e^8)
      float mnew = fmaxf(m_run, mx);
      float sc = fast_exp2(m_run - mnew);
      m_run = mnew;
      l_run *= sc;
#pragma unroll
      for (int r = 0; r < 4; ++r) {
        float scr = __shfl(sc, lh * 4 + r);        // sc of output row lh*4+r
#pragma unroll
        for (int ni = 0; ni < 4; ++ni) oacc[ni][r] *= scr;
      }
    }
    float rs = 0.f;
#pragma unroll
    for (int t = 0; t < 4; ++t)
#pragma unroll
      for (int r = 0; r < 4; ++r) {
        float pv = fast_exp2(p[t][r] - m_run);
        p[t][r] = pv;
        rs += pv;
      }
    rs += __shfl_xor(rs, 16);
    rs += __shfl_xor(rs, 32);
    l_run += rs;
    // pack P in-register: pa0 slot(lh,e) holds k=16*(e/4)+4*lh+(e&3); V cols permuted to match
    uint32_t pk[4][2];
#pragma unroll
    for (int t = 0; t < 4; ++t) {
      asm("v_cvt_pk_bf16_f32 %0, %1, %2" : "=v"(pk[t][0]) : "v"(p[t][0]), "v"(p[t][1]));
      asm("v_cvt_pk_bf16_f32 %0, %1, %2" : "=v"(pk[t][1]) : "v"(p[t][2]), "v"(p[t][3]));
    }
    u32x4 A0 = {pk[0][0], pk[0][1], pk[1][0], pk[1][1]};
    u32x4 A1 = {pk[2][0], pk[2][1], pk[3][0], pk[3][1]};
    bf16x8 pa0 = __builtin_bit_cast(bf16x8, A0);
    bf16x8 pa1 = __builtin_bit_cast(bf16x8, A1);
    // PV
    {
      const char* vbr = (const char*)&Vs[cur][0];
      __builtin_amdgcn_s_setprio(1);
#pragma unroll
      for (int ni = 0; ni < 4; ++ni) {
        int vrow = ni * 16 + lr;
        bf16x8 v0 = *(const bf16x8*)(vbr + vrow * 128 + ((lh * 16) ^ swz(vrow)));
        bf16x8 v1 = *(const bf16x8*)(vbr + vrow * 128 + ((64 + lh * 16) ^ swz(vrow)));
        oacc[ni] = __builtin_amdgcn_mfma_f32_16x16x32_bf16(pa0, v0, oacc[ni], 0, 0, 0);
        oacc[ni] = __builtin_amdgcn_mfma_f32_16x16x32_bf16(pa1, v1, oacc[ni], 0, 0, 0);
      }
      __builtin_amdgcn_s_setprio(0);
    }
    __syncthreads();
  }

#pragma unroll
  for (int r = 0; r < 4; ++r) {
    float linv = 1.0f / __shfl(l_run, lh * 4 + r);
    int s = q0 + w * 16 + lh * 4 + r;
#pragma unroll
    for (int ni = 0; ni < 4; ++ni) {
      int dh = ni * 16 + lr;
      ao[((size_t)(b * 2048 + s)) * 512 + h * 64 + dh] = (__bf16)(oacc[ni][r] * linv);
    }
  }
}

extern "C" void kernel_launch(void* const* d_in, const int* in_sizes, int n_in,
                              void* d_out, int out_size, void* d_ws, size_t ws_size,
                              hipStream_t stream) {
  (void)in_sizes; (void)n_in; (void)out_size; (void)ws_size;
  const float* hs = (const float*)d_in[0];
  const float* Wq = (const float*)d_in[1];
  const float* Wk = (const float*)d_in[2];
  const float* Wv = (const float*)d_in[3];
  const float* Wo = (const float*)d_in[4];
  const float* rb = (const float*)d_in[5];
  char* ws = (char*)d_ws;
  __bf16* hs2    = (__bf16*)(ws + OFF_HS2);
  __bf16* wqkv2  = (__bf16*)(ws + OFF_WQKV2);
  __bf16* wo_t   = (__bf16*)(ws + OFF_WO);
  __bf16* qhb    = (__bf16*)(ws + OFF_QH);
  __bf16* qlb    = (__bf16*)(ws + OFF_QL);
  __bf16* kb     = (__bf16*)(ws + OFF_K);
  __bf16* vb     = (__bf16*)(ws + OFF_V);
  __bf16* vtb    = (__bf16*)(ws + OFF_VT);
  __bf16* aob    = (__bf16*)(ws + OFF_AO);
  float*  bias   = (float*)(ws + OFF_BIAS);

  k_cast_hs2<<<2048, 256, 0, stream>>>(hs, hs2);
  k_prep_w2<<<dim3(8, 8, 3), 256, 0, stream>>>(Wq, Wk, Wv, wqkv2);
  k_prep_wo<<<1024, 256, 0, stream>>>(Wo, wo_t);
  k_bias<<<128, 256, 0, stream>>>(rb, bias);
  k_gemm<0, 48, 1024, 1536><<<dim3(12, 64), 256, 0, stream>>>(hs2, wqkv2, qhb, qlb, kb, vb, nullptr);
  k_transv<<<dim3(32, 32), 256, 0, stream>>>(vb, vtb);
  k_attn<<<dim3(512), 512, 0, stream>>>(qhb, qlb, kb, vtb, bias, aob);
  k_gemm<1, 16, 512, 512><<<dim3(4, 64), 256, 0, stream>>>(aob, wo_t, nullptr, nullptr, nullptr, nullptr, (float*)d_out);
}

// Round 11
// 145.792 us; speedup vs baseline: 1.1282x; 1.0468x over previous
//
#include <hip/hip_runtime.h>
#include <stdint.h>

typedef __attribute__((ext_vector_type(8))) __bf16 bf16x8;
typedef __attribute__((ext_vector_type(4))) __bf16 bf16x4;
typedef __attribute__((ext_vector_type(4))) float f32x4;
typedef __attribute__((ext_vector_type(4))) unsigned int u32x4;

#define SEQ 2048
#define LOG2E 1.4426950408889634f

// ---------- ws layout (bytes) ----------
#define OFF_HS2   0ull               // bf16 [8192][1024]  ([hi|lo] along K)
#define OFF_VT    0ull               // bf16 [32][64][2048]   (overlay, after GEMM; k-permuted cols)
#define OFF_AO    8388608ull         // bf16 [8192][512]      (overlay, after GEMM)
#define OFF_WQKV2 16777216ull        // bf16 [1536][1536]  (w_t[n][k'], k'=[hi|hi|lo]; Wq pre-scaled by log2e)
#define OFF_WO    21495808ull        // bf16 [512][512]
#define OFF_QH    22020096ull        // bf16 [32][2048][64]
#define OFF_QL    30408704ull
#define OFF_K     38797312ull
#define OFF_V     47185920ull
#define OFF_BIAS  55574528ull        // f32 [8][4096]  (scaled by log2e)

__device__ __forceinline__ int swz(int row) { return ((row & 7) << 4) ^ ((row & 8) << 1); }

__device__ __forceinline__ void gl_lds16(const void* g, void* l) {
  __builtin_amdgcn_global_load_lds(
      (__attribute__((address_space(1))) void*)(uintptr_t)g,
      (__attribute__((address_space(3))) void*)(uint32_t)(uintptr_t)l, 16, 0, 0);
}

// raw v_exp_f32 (2^x), 1-ulp hardware transcendental
__device__ __forceinline__ float fast_exp2(float x) { return __builtin_amdgcn_exp2f(x); }

// ---------- prep: hidden_states f32 -> [hi|lo] bf16, K' = 1024 (read once) ----------
__global__ void k_cast_hs2(const float* __restrict__ hs, __bf16* __restrict__ out) {
  int gid = blockIdx.x * 256 + threadIdx.x;       // 524288
  int row = gid >> 6, c8 = (gid & 63) * 8;
  const float* p = hs + (size_t)row * 512 + c8;
  float4 a = *(const float4*)p, b = *(const float4*)(p + 4);
  float v[8] = {a.x, a.y, a.z, a.w, b.x, b.y, b.z, b.w};
  bf16x8 hi, lo;
#pragma unroll
  for (int j = 0; j < 8; ++j) {
    __bf16 h = (__bf16)v[j];
    hi[j] = h;
    lo[j] = (__bf16)(v[j] - (float)h);
  }
  *(bf16x8*)(out + (size_t)row * 1024 + c8) = hi;
  *(bf16x8*)(out + (size_t)row * 1024 + 512 + c8) = lo;
}

// ---------- prep: QKV weights -> transposed split [1536][1536]; Wq scaled by log2e ----------
__global__ void k_prep_w2(const float* __restrict__ Wq, const float* __restrict__ Wk,
                          const float* __restrict__ Wv, __bf16* __restrict__ w2) {
  __shared__ float tile[64][65];
  int z = blockIdx.z;
  const float* W = (z == 0) ? Wq : (z == 1) ? Wk : Wv;
  float scale = (z == 0) ? LOG2E : 1.0f;
  int k0 = blockIdx.y * 64, n0 = blockIdx.x * 64;
  int tx = threadIdx.x & 63, ty = threadIdx.x >> 6;
  for (int r = ty; r < 64; r += 4) tile[r][tx] = W[(size_t)(k0 + r) * 512 + n0 + tx];
  __syncthreads();
  for (int r = ty; r < 64; r += 4) {
    float v = tile[tx][r] * scale;               // (k=k0+tx, n=n0+r)
    __bf16 h = (__bf16)v;
    __bf16 lo = (__bf16)(v - (float)h);
    __bf16* dst = w2 + (size_t)(z * 512 + n0 + r) * 1536;
    dst[k0 + tx] = h;
    dst[512 + k0 + tx] = h;
    dst[1024 + k0 + tx] = lo;
  }
}

__global__ void k_prep_wo(const float* __restrict__ Wo, __bf16* __restrict__ wo_t) {
  int idx = blockIdx.x * 256 + threadIdx.x;
  int n = idx >> 9, k = idx & 511;
  wo_t[idx] = (__bf16)Wo[(size_t)k * 512 + n];
}

// ---------- prep: T5 relative-position bias table (log2e-scaled) ----------
__global__ void k_bias(const float* __restrict__ rel_bias, float* __restrict__ bias_tab) {
  int idx = blockIdx.x * 256 + threadIdx.x;
  int h = idx >> 12, dIdx = idx & 4095;
  float v = 0.f;
  if (dIdx < 4095) {
    int d = dIdx - 2047;
    int rp = d < 0 ? -d : d;
    int bp;
    if (rp < 8) bp = rp;
    else bp = 8 + (rp >= 12) + (rp >= 16) + (rp >= 23) + (rp >= 32) + (rp >= 46) + (rp >= 64) + (rp >= 91);
    v = rel_bias[((d > 0 ? 16 : 0) + bp) * 8 + h] * LOG2E;
  }
  bias_tab[idx] = v;
}

// ---------- GEMM; MODE 0: QKV split (Q 48, K 32, V 16 K-steps) ----------
template <int MODE, int KSTEPS, int LDA, int LDB>
__global__ __launch_bounds__(256) void k_gemm(const __bf16* __restrict__ A,
                                              const __bf16* __restrict__ Bt,
                                              __bf16* __restrict__ qh, __bf16* __restrict__ ql,
                                              __bf16* __restrict__ ko, __bf16* __restrict__ vo,
                                              float* __restrict__ fo) {
  __shared__ __align__(16) __bf16 As[2][128 * 32];
  __shared__ __align__(16) __bf16 Bs[2][128 * 32];
  int tid = threadIdx.x, w = tid >> 6, l = tid & 63;
  int lr = l & 15, lh = l >> 4;
  int m0 = blockIdx.y * 128, n0 = blockIdx.x * 128;
  int wm = (w >> 1) * 64, wn = (w & 1) * 64;
  // Q (n0<512): full split 48; K (512..1023): drop A_hi*W_lo -> 32; V (>=1024): plain 16
  int ksteps = (MODE == 0) ? (n0 >= 1024 ? 16 : (n0 >= 512 ? 32 : 48)) : KSTEPS;
  f32x4 zero4 = {0.f, 0.f, 0.f, 0.f};
  f32x4 acc[4][4];
#pragma unroll
  for (int i = 0; i < 4; ++i)
#pragma unroll
    for (int j = 0; j < 4; ++j) acc[i][j] = zero4;

  auto stage = [&](int kt, int buf) {
    int ka = (MODE == 0 && kt >= 32) ? kt - 32 : kt;
#pragma unroll
    for (int c = 0; c < 2; ++c) {
      int i = c * 256 + w * 64 + l;
      int row = i >> 2, cc = i & 3;
      gl_lds16(A + (size_t)(m0 + row) * LDA + ka * 32 + cc * 8,
               (char*)&As[buf][0] + (c * 256 + w * 64) * 16);
      gl_lds16(Bt + (size_t)(n0 + row) * LDB + kt * 32 + cc * 8,
               (char*)&Bs[buf][0] + (c * 256 + w * 64) * 16);
    }
  };

  stage(0, 0);
  __syncthreads();
  int cur = 0;
  for (int kt = 0; kt < ksteps; ++kt) {
    if (kt + 1 < ksteps) stage(kt + 1, cur ^ 1);
    bf16x8 af[4], bfr[4];
#pragma unroll
    for (int mi = 0; mi < 4; ++mi)
      af[mi] = *(const bf16x8*)&As[cur][(wm + mi * 16 + lr) * 32 + lh * 8];
#pragma unroll
    for (int ni = 0; ni < 4; ++ni)
      bfr[ni] = *(const bf16x8*)&Bs[cur][(wn + ni * 16 + lr) * 32 + lh * 8];
#pragma unroll
    for (int mi = 0; mi < 4; ++mi)
#pragma unroll
      for (int ni = 0; ni < 4; ++ni)
        acc[mi][ni] = __builtin_amdgcn_mfma_f32_16x16x32_bf16(af[mi], bfr[ni], acc[mi][ni], 0, 0, 0);
    __syncthreads();
    cur ^= 1;
  }

#pragma unroll
  for (int mi = 0; mi < 4; ++mi)
#pragma unroll
    for (int ni = 0; ni < 4; ++ni)
#pragma unroll
      for (int r = 0; r < 4; ++r) {
        int m = m0 + wm + mi * 16 + lh * 4 + r;
        int n = n0 + wn + ni * 16 + lr;
        float vv = acc[mi][ni][r];
        if (MODE == 0) {
          int which = n >> 9, c9 = n & 511, hh = c9 >> 6, dh = c9 & 63;
          int b = m >> 11, s = m & 2047;
          size_t o = (size_t)((b * 8 + hh) * 2048 + s) * 64 + dh;
          if (which == 0) {
            __bf16 hv = (__bf16)vv;
            qh[o] = hv;
            ql[o] = (__bf16)(vv - (float)hv);
          } else if (which == 1) {
            ko[o] = (__bf16)vv;
          } else {
            vo[o] = (__bf16)vv;
          }
        } else {
          fo[(size_t)m * 512 + n] = vv;
        }
      }
}

// ---------- transpose V to [bh][dh][s], with per-64 k-column permutation ----------
// dest 4-col group d2 for source group c2:  k = 32a+16u+4m+v  ->  p = 32a+8m+4u+v
__global__ void k_transv(const __bf16* __restrict__ v, __bf16* __restrict__ vt) {
  __shared__ __bf16 t[64][72];
  int bh = blockIdx.y, s0 = blockIdx.x * 64, tid = threadIdx.x;
  const __bf16* src = v + (size_t)bh * SEQ * 64;
  __bf16* dst = vt + (size_t)bh * 64 * SEQ;
#pragma unroll
  for (int c = 0; c < 2; ++c) {
    int i = c * 256 + tid, row = i >> 3, col = (i & 7) * 8;
    *(bf16x8*)&t[row][col] = *(const bf16x8*)&src[(size_t)(s0 + row) * 64 + col];
  }
  __syncthreads();
#pragma unroll
  for (int c = 0; c < 2; ++c) {
    int i = c * 256 + tid, dh = i >> 3, c8 = i & 7;
    bf16x4 o1, o2;
#pragma unroll
    for (int j = 0; j < 4; ++j) { o1[j] = t[c8 * 8 + j][dh]; o2[j] = t[c8 * 8 + 4 + j][dh]; }
    int c2a = 2 * c8, c2b = 2 * c8 + 1;
    int d2a = ((c2a >> 3) << 3) | ((c2a & 3) << 1) | ((c2a >> 2) & 1);
    int d2b = ((c2b >> 3) << 3) | ((c2b & 3) << 1) | ((c2b >> 2) & 1);
    *(bf16x4*)&dst[(size_t)dh * SEQ + s0 + 4 * d2a] = o1;
    *(bf16x4*)&dst[(size_t)dh * SEQ + s0 + 4 * d2b] = o2;
  }
}

// ---------- flash attention: swapped QK^T, register P, exp2 domain, far-tile bias ----------
__global__ __launch_bounds__(512) void k_attn(const __bf16* __restrict__ qhp,
                                              const __bf16* __restrict__ qlp,
                                              const __bf16* __restrict__ k,
                                              const __bf16* __restrict__ vt,
                                              const float* __restrict__ bias_tab,
                                              __bf16* __restrict__ ao) {
  __shared__ __align__(16) __bf16 Ks[2][64 * 64];
  __shared__ __align__(16) __bf16 Vs[2][64 * 64];
  __shared__ float bias_s[2176];
  int tid = threadIdx.x, w = tid >> 6, l = tid & 63;
  int lr = l & 15, lh = l >> 4;
  int d = blockIdx.x;
  int bh = (d & 7) + ((d >> 3) & 3) * 8;
  int q0 = (d >> 5) * 128;
  int h = bh & 7, b = bh >> 3;
  const char* kbase = (const char*)(k + (size_t)bh * SEQ * 64);
  const char* vbase = (const char*)(vt + (size_t)bh * 64 * SEQ);

  // far-diagonal bias constants (bucket saturates at |d|>=91)
  float bR = bias_tab[h * 4096 + 2047 + 200];
  float bL = bias_tab[h * 4096 + 2047 - 200];

  for (int j = tid; j < 2176; j += 512)
    bias_s[j] = bias_tab[h * 4096 + (1920 - q0) + j];

  auto stageKV = [&](int kt, int buf) {
    const char* kb = kbase + (size_t)kt * 64 * 128;
    const char* vb = vbase + (size_t)kt * 128;
    int row = tid >> 3, colb = (tid & 7) * 16;
    gl_lds16(kb + row * 128 + (colb ^ swz(row)), (char*)&Ks[buf][0] + tid * 16);
    gl_lds16(vb + (size_t)row * 4096 + (colb ^ swz(row)), (char*)&Vs[buf][0] + tid * 16);
  };

  // Q fragments straight from global (per-lane 16B reads; no LDS round-trip)
  bf16x8 qfh[2], qfl[2];
  int qrow = w * 16 + lr;
  {
    const __bf16* qg = qhp + ((size_t)bh * SEQ + q0 + qrow) * 64;
    qfh[0] = *(const bf16x8*)(qg + lh * 8);
    qfh[1] = *(const bf16x8*)(qg + 32 + lh * 8);
    const __bf16* qg2 = qlp + ((size_t)bh * SEQ + q0 + qrow) * 64;
    qfl[0] = *(const bf16x8*)(qg2 + lh * 8);
    qfl[1] = *(const bf16x8*)(qg2 + 32 + lh * 8);
  }
  stageKV(0, 0);
  __syncthreads();

  float m_run = -1e30f, l_run = 0.f;
  f32x4 zero4 = {0.f, 0.f, 0.f, 0.f};
  f32x4 oacc[4];
#pragma unroll
  for (int i = 0; i < 4; ++i) oacc[i] = zero4;

#pragma unroll 2
  for (int kt = 0; kt < 32; ++kt) {
    int cur = kt & 1;
    if (kt + 1 < 32) stageKV(kt + 1, cur ^ 1);
    const char* kb = (const char*)&Ks[cur][0];
    f32x4 sacc[4];
    __builtin_amdgcn_s_setprio(1);
#pragma unroll
    for (int t = 0; t < 4; ++t) {
      int row = t * 16 + lr;
      bf16x8 b0 = *(const bf16x8*)(kb + row * 128 + ((lh * 16) ^ swz(row)));
      bf16x8 b1 = *(const bf16x8*)(kb + row * 128 + ((64 + lh * 16) ^ swz(row)));
      f32x4 z = zero4;
      z = __builtin_amdgcn_mfma_f32_16x16x32_bf16(b0, qfh[0], z, 0, 0, 0);
      z = __builtin_amdgcn_mfma_f32_16x16x32_bf16(b1, qfh[1], z, 0, 0, 0);
      z = __builtin_amdgcn_mfma_f32_16x16x32_bf16(b0, qfl[0], z, 0, 0, 0);
      z = __builtin_amdgcn_mfma_f32_16x16x32_bf16(b1, qfl[1], z, 0, 0, 0);
      sacc[t] = z;
    }
    __builtin_amdgcn_s_setprio(0);
    // lane (lr,lh) reg (t,r): S[q = q0+w*16+lr][k = kt*64 + t*16 + lh*4 + r]  (log2 domain)
    float p[4][4];
    float mx = -1e30f;
    int dmin = kt * 64 - q0 - 127, dmax = kt * 64 + 63 - q0;
    if (dmin >= 91 || dmax <= -91) {               // far tile: bias is per-head constant
      float cb = (dmin >= 91) ? bR : bL;
#pragma unroll
      for (int t = 0; t < 4; ++t)
#pragma unroll
        for (int r = 0; r < 4; ++r) {
          float sv = sacc[t][r] + cb;
          p[t][r] = sv;
          mx = fmaxf(mx, sv);
        }
    } else {                                       // diagonal band: per-element bias
      int jb = kt * 64 + lh * 4 + 127 - (w * 16 + lr);
#pragma unroll
      for (int t = 0; t < 4; ++t)
#pragma unroll
        for (int r = 0; r < 4; ++r) {
          float sv = sacc[t][r] + bias_s[jb + t * 16 + r];
          p[t][r] = sv;
          mx = fmaxf(mx, sv);
        }
    }
    mx = fmaxf(mx, __shfl_xor(mx, 16));
    mx = fmaxf(mx, __shfl_xor(mx, 32));
    if (!__all(mx <= m_run + 11.5f)) {             // defer-max (2^11.5 ~ e^8)
      float mnew = fmaxf(m_run, mx);
      float sc = fast_exp2(m_run - mnew);
      m_run = mnew;
      l_run *= sc;
#pragma unroll
      for (int r = 0; r < 4; ++r) {
        float scr = __shfl(sc, lh * 4 + r);        // sc of output row lh*4+r
#pragma unroll
        for (int ni = 0; ni < 4; ++ni) oacc[ni][r] *= scr;
      }
    }
    float rs = 0.f;
#pragma unroll
    for (int t = 0; t < 4; ++t)
#pragma unroll
      for (int r = 0; r < 4; ++r) {
        float pv = fast_exp2(p[t][r] - m_run);
        p[t][r] = pv;
        rs += pv;
      }
    rs += __shfl_xor(rs, 16);
    rs += __shfl_xor(rs, 32);
    l_run += rs;
    // pack P in-register: pa0 slot(lh,e) holds k=16*(e/4)+4*lh+(e&3); V cols permuted to match
    uint32_t pk[4][2];
#pragma unroll
    for (int t = 0; t < 4; ++t) {
      asm("v_cvt_pk_bf16_f32 %0, %1, %2" : "=v"(pk[t][0]) : "v"(p[t][0]), "v"(p[t][1]));
      asm("v_cvt_pk_bf16_f32 %0, %1, %2" : "=v"(pk[t][1]) : "v"(p[t][2]), "v"(p[t][3]));
    }
    u32x4 A0 = {pk[0][0], pk[0][1], pk[1][0], pk[1][1]};
    u32x4 A1 = {pk[2][0], pk[2][1], pk[3][0], pk[3][1]};
    bf16x8 pa0 = __builtin_bit_cast(bf16x8, A0);
    bf16x8 pa1 = __builtin_bit_cast(bf16x8, A1);
    // PV
    {
      const char* vbr = (const char*)&Vs[cur][0];
      __builtin_amdgcn_s_setprio(1);
#pragma unroll
      for (int ni = 0; ni < 4; ++ni) {
        int vrow = ni * 16 + lr;
        bf16x8 v0 = *(const bf16x8*)(vbr + vrow * 128 + ((lh * 16) ^ swz(vrow)));
        bf16x8 v1 = *(const bf16x8*)(vbr + vrow * 128 + ((64 + lh * 16) ^ swz(vrow)));
        oacc[ni] = __builtin_amdgcn_mfma_f32_16x16x32_bf16(pa0, v0, oacc[ni], 0, 0, 0);
        oacc[ni] = __builtin_amdgcn_mfma_f32_16x16x32_bf16(pa1, v1, oacc[ni], 0, 0, 0);
      }
      __builtin_amdgcn_s_setprio(0);
    }
    __syncthreads();
  }

#pragma unroll
  for (int r = 0; r < 4; ++r) {
    float linv = 1.0f / __shfl(l_run, lh * 4 + r);
    int s = q0 + w * 16 + lh * 4 + r;
#pragma unroll
    for (int ni = 0; ni < 4; ++ni) {
      int dh = ni * 16 + lr;
      ao[((size_t)(b * 2048 + s)) * 512 + h * 64 + dh] = (__bf16)(oacc[ni][r] * linv);
    }
  }
}

extern "C" void kernel_launch(void* const* d_in, const int* in_sizes, int n_in,
                              void* d_out, int out_size, void* d_ws, size_t ws_size,
                              hipStream_t stream) {
  (void)in_sizes; (void)n_in; (void)out_size; (void)ws_size;
  const float* hs = (const float*)d_in[0];
  const float* Wq = (const float*)d_in[1];
  const float* Wk = (const float*)d_in[2];
  const float* Wv = (const float*)d_in[3];
  const float* Wo = (const float*)d_in[4];
  const float* rb = (const float*)d_in[5];
  char* ws = (char*)d_ws;
  __bf16* hs2    = (__bf16*)(ws + OFF_HS2);
  __bf16* wqkv2  = (__bf16*)(ws + OFF_WQKV2);
  __bf16* wo_t   = (__bf16*)(ws + OFF_WO);
  __bf16* qhb    = (__bf16*)(ws + OFF_QH);
  __bf16* qlb    = (__bf16*)(ws + OFF_QL);
  __bf16* kb     = (__bf16*)(ws + OFF_K);
  __bf16* vb     = (__bf16*)(ws + OFF_V);
  __bf16* vtb    = (__bf16*)(ws + OFF_VT);
  __bf16* aob    = (__bf16*)(ws + OFF_AO);
  float*  bias   = (float*)(ws + OFF_BIAS);

  k_cast_hs2<<<2048, 256, 0, stream>>>(hs, hs2);
  k_prep_w2<<<dim3(8, 8, 3), 256, 0, stream>>>(Wq, Wk, Wv, wqkv2);
  k_prep_wo<<<1024, 256, 0, stream>>>(Wo, wo_t);
  k_bias<<<128, 256, 0, stream>>>(rb, bias);
  k_gemm<0, 48, 1024, 1536><<<dim3(12, 64), 256, 0, stream>>>(hs2, wqkv2, qhb, qlb, kb, vb, nullptr);
  k_transv<<<dim3(32, 32), 256, 0, stream>>>(vb, vtb);
  k_attn<<<dim3(512), 512, 0, stream>>>(qhb, qlb, kb, vtb, bias, aob);
  k_gemm<1, 16, 512, 512><<<dim3(4, 64), 256, 0, stream>>>(aob, wo_t, nullptr, nullptr, nullptr, nullptr, (float*)d_out);
}

// Round 12
// 141.498 us; speedup vs baseline: 1.1624x; 1.0303x over previous
//
#include <hip/hip_runtime.h>
#include <stdint.h>

typedef __attribute__((ext_vector_type(8))) __bf16 bf16x8;
typedef __attribute__((ext_vector_type(4))) __bf16 bf16x4;
typedef __attribute__((ext_vector_type(4))) float f32x4;
typedef __attribute__((ext_vector_type(4))) unsigned int u32x4;

#define SEQ 2048
#define LOG2E 1.4426950408889634f

// ---------- ws layout (bytes) ----------
#define OFF_HS2   0ull               // bf16 [8192][1024]  ([hi|lo] along K)
#define OFF_VT    0ull               // bf16 [32][64][2048]   (overlay, after GEMM; k-permuted cols)
#define OFF_AO    8388608ull         // bf16 [8192][512]      (overlay, after GEMM)
#define OFF_WQKV2 16777216ull        // bf16 [1536][1536]  (w_t[n][k'], k'=[hi|hi|lo]; Wq pre-scaled by log2e)
#define OFF_WO    21495808ull        // bf16 [512][512]
#define OFF_QH    22020096ull        // bf16 [32][2048][64]
#define OFF_QL    30408704ull
#define OFF_K     38797312ull
#define OFF_V     47185920ull
#define OFF_BIAS  55574528ull        // f32 [8][4096]  (scaled by log2e)

__device__ __forceinline__ int swz(int row) { return ((row & 7) << 4) ^ ((row & 8) << 1); }

__device__ __forceinline__ void gl_lds16(const void* g, void* l) {
  __builtin_amdgcn_global_load_lds(
      (__attribute__((address_space(1))) void*)(uintptr_t)g,
      (__attribute__((address_space(3))) void*)(uint32_t)(uintptr_t)l, 16, 0, 0);
}

// raw v_exp_f32 (2^x), 1-ulp hardware transcendental
__device__ __forceinline__ float fast_exp2(float x) { return __builtin_amdgcn_exp2f(x); }

// ---------- prep: hidden_states f32 -> [hi|lo] bf16, K' = 1024 (read once) ----------
__global__ void k_cast_hs2(const float* __restrict__ hs, __bf16* __restrict__ out) {
  int gid = blockIdx.x * 256 + threadIdx.x;       // 524288
  int row = gid >> 6, c8 = (gid & 63) * 8;
  const float* p = hs + (size_t)row * 512 + c8;
  float4 a = *(const float4*)p, b = *(const float4*)(p + 4);
  float v[8] = {a.x, a.y, a.z, a.w, b.x, b.y, b.z, b.w};
  bf16x8 hi, lo;
#pragma unroll
  for (int j = 0; j < 8; ++j) {
    __bf16 h = (__bf16)v[j];
    hi[j] = h;
    lo[j] = (__bf16)(v[j] - (float)h);
  }
  *(bf16x8*)(out + (size_t)row * 1024 + c8) = hi;
  *(bf16x8*)(out + (size_t)row * 1024 + 512 + c8) = lo;
}

// ---------- prep: QKV weights -> transposed split [1536][1536]; Wq scaled by log2e ----------
__global__ void k_prep_w2(const float* __restrict__ Wq, const float* __restrict__ Wk,
                          const float* __restrict__ Wv, __bf16* __restrict__ w2) {
  __shared__ float tile[64][65];
  int z = blockIdx.z;
  const float* W = (z == 0) ? Wq : (z == 1) ? Wk : Wv;
  float scale = (z == 0) ? LOG2E : 1.0f;
  int k0 = blockIdx.y * 64, n0 = blockIdx.x * 64;
  int tx = threadIdx.x & 63, ty = threadIdx.x >> 6;
  for (int r = ty; r < 64; r += 4) tile[r][tx] = W[(size_t)(k0 + r) * 512 + n0 + tx];
  __syncthreads();
  for (int r = ty; r < 64; r += 4) {
    float v = tile[tx][r] * scale;               // (k=k0+tx, n=n0+r)
    __bf16 h = (__bf16)v;
    __bf16 lo = (__bf16)(v - (float)h);
    __bf16* dst = w2 + (size_t)(z * 512 + n0 + r) * 1536;
    dst[k0 + tx] = h;
    dst[512 + k0 + tx] = h;
    dst[1024 + k0 + tx] = lo;
  }
}

__global__ void k_prep_wo(const float* __restrict__ Wo, __bf16* __restrict__ wo_t) {
  int idx = blockIdx.x * 256 + threadIdx.x;
  int n = idx >> 9, k = idx & 511;
  wo_t[idx] = (__bf16)Wo[(size_t)k * 512 + n];
}

// ---------- prep: T5 relative-position bias table (log2e-scaled) ----------
__global__ void k_bias(const float* __restrict__ rel_bias, float* __restrict__ bias_tab) {
  int idx = blockIdx.x * 256 + threadIdx.x;
  int h = idx >> 12, dIdx = idx & 4095;
  float v = 0.f;
  if (dIdx < 4095) {
    int d = dIdx - 2047;
    int rp = d < 0 ? -d : d;
    int bp;
    if (rp < 8) bp = rp;
    else bp = 8 + (rp >= 12) + (rp >= 16) + (rp >= 23) + (rp >= 32) + (rp >= 46) + (rp >= 64) + (rp >= 91);
    v = rel_bias[((d > 0 ? 16 : 0) + bp) * 8 + h] * LOG2E;
  }
  bias_tab[idx] = v;
}

// ---------- GEMM; MODE 0: QKV split (Q 48, K 32, V 16 K-steps); XCD-swizzled grid ----------
template <int MODE, int KSTEPS, int LDA, int LDB>
__global__ __launch_bounds__(256) void k_gemm(const __bf16* __restrict__ A,
                                              const __bf16* __restrict__ Bt,
                                              __bf16* __restrict__ qh, __bf16* __restrict__ ql,
                                              __bf16* __restrict__ ko, __bf16* __restrict__ vo,
                                              float* __restrict__ fo) {
  __shared__ __align__(16) __bf16 As[2][128 * 32];
  __shared__ __align__(16) __bf16 Bs[2][128 * 32];
  int tid = threadIdx.x, w = tid >> 6, l = tid & 63;
  int lr = l & 15, lh = l >> 4;
  // XCD-aware bijective remap (nwg % 8 == 0 for both modes): each XCD gets
  // contiguous m-rows -> A panels stay in one XCD's L2.
  int nwg = gridDim.x * gridDim.y;
  int flat = blockIdx.y * gridDim.x + blockIdx.x;
  int flat2 = (flat & 7) * (nwg >> 3) + (flat >> 3);
  int m0 = (flat2 / gridDim.x) * 128, n0 = (flat2 % gridDim.x) * 128;
  int wm = (w >> 1) * 64, wn = (w & 1) * 64;
  // Q (n0<512): full split 48; K (512..1023): drop A_hi*W_lo -> 32; V (>=1024): plain 16
  int ksteps = (MODE == 0) ? (n0 >= 1024 ? 16 : (n0 >= 512 ? 32 : 48)) : KSTEPS;
  f32x4 zero4 = {0.f, 0.f, 0.f, 0.f};
  f32x4 acc[4][4];
#pragma unroll
  for (int i = 0; i < 4; ++i)
#pragma unroll
    for (int j = 0; j < 4; ++j) acc[i][j] = zero4;

  auto stage = [&](int kt, int buf) {
    int ka = (MODE == 0 && kt >= 32) ? kt - 32 : kt;
#pragma unroll
    for (int c = 0; c < 2; ++c) {
      int i = c * 256 + w * 64 + l;
      int row = i >> 2, cc = i & 3;
      gl_lds16(A + (size_t)(m0 + row) * LDA + ka * 32 + cc * 8,
               (char*)&As[buf][0] + (c * 256 + w * 64) * 16);
      gl_lds16(Bt + (size_t)(n0 + row) * LDB + kt * 32 + cc * 8,
               (char*)&Bs[buf][0] + (c * 256 + w * 64) * 16);
    }
  };

  stage(0, 0);
  __syncthreads();
  int cur = 0;
  for (int kt = 0; kt < ksteps; ++kt) {
    if (kt + 1 < ksteps) stage(kt + 1, cur ^ 1);
    bf16x8 af[4], bfr[4];
#pragma unroll
    for (int mi = 0; mi < 4; ++mi)
      af[mi] = *(const bf16x8*)&As[cur][(wm + mi * 16 + lr) * 32 + lh * 8];
#pragma unroll
    for (int ni = 0; ni < 4; ++ni)
      bfr[ni] = *(const bf16x8*)&Bs[cur][(wn + ni * 16 + lr) * 32 + lh * 8];
#pragma unroll
    for (int mi = 0; mi < 4; ++mi)
#pragma unroll
      for (int ni = 0; ni < 4; ++ni)
        acc[mi][ni] = __builtin_amdgcn_mfma_f32_16x16x32_bf16(af[mi], bfr[ni], acc[mi][ni], 0, 0, 0);
    __syncthreads();
    cur ^= 1;
  }

#pragma unroll
  for (int mi = 0; mi < 4; ++mi)
#pragma unroll
    for (int ni = 0; ni < 4; ++ni)
#pragma unroll
      for (int r = 0; r < 4; ++r) {
        int m = m0 + wm + mi * 16 + lh * 4 + r;
        int n = n0 + wn + ni * 16 + lr;
        float vv = acc[mi][ni][r];
        if (MODE == 0) {
          int which = n >> 9, c9 = n & 511, hh = c9 >> 6, dh = c9 & 63;
          int b = m >> 11, s = m & 2047;
          size_t o = (size_t)((b * 8 + hh) * 2048 + s) * 64 + dh;
          if (which == 0) {
            __bf16 hv = (__bf16)vv;
            qh[o] = hv;
            ql[o] = (__bf16)(vv - (float)hv);
          } else if (which == 1) {
            ko[o] = (__bf16)vv;
          } else {
            vo[o] = (__bf16)vv;
          }
        } else {
          fo[(size_t)m * 512 + n] = vv;
        }
      }
}

// ---------- transpose V to [bh][dh][s], with per-64 k-column permutation ----------
// dest 4-col group d2 for source group c2:  k = 32a+16u+4m+v  ->  p = 32a+8m+4u+v
__global__ void k_transv(const __bf16* __restrict__ v, __bf16* __restrict__ vt) {
  __shared__ __bf16 t[64][72];
  int bh = blockIdx.y, s0 = blockIdx.x * 64, tid = threadIdx.x;
  const __bf16* src = v + (size_t)bh * SEQ * 64;
  __bf16* dst = vt + (size_t)bh * 64 * SEQ;
#pragma unroll
  for (int c = 0; c < 2; ++c) {
    int i = c * 256 + tid, row = i >> 3, col = (i & 7) * 8;
    *(bf16x8*)&t[row][col] = *(const bf16x8*)&src[(size_t)(s0 + row) * 64 + col];
  }
  __syncthreads();
#pragma unroll
  for (int c = 0; c < 2; ++c) {
    int i = c * 256 + tid, dh = i >> 3, c8 = i & 7;
    bf16x4 o1, o2;
#pragma unroll
    for (int j = 0; j < 4; ++j) { o1[j] = t[c8 * 8 + j][dh]; o2[j] = t[c8 * 8 + 4 + j][dh]; }
    int c2a = 2 * c8, c2b = 2 * c8 + 1;
    int d2a = ((c2a >> 3) << 3) | ((c2a & 3) << 1) | ((c2a >> 2) & 1);
    int d2b = ((c2b >> 3) << 3) | ((c2b & 3) << 1) | ((c2b >> 2) & 1);
    *(bf16x4*)&dst[(size_t)dh * SEQ + s0 + 4 * d2a] = o1;
    *(bf16x4*)&dst[(size_t)dh * SEQ + s0 + 4 * d2b] = o2;
  }
}

// ---------- flash attention: swapped QK^T, register P, exp2 domain, lazy reductions ----------
__global__ __launch_bounds__(512) void k_attn(const __bf16* __restrict__ qhp,
                                              const __bf16* __restrict__ qlp,
                                              const __bf16* __restrict__ k,
                                              const __bf16* __restrict__ vt,
                                              const float* __restrict__ bias_tab,
                                              __bf16* __restrict__ ao) {
  __shared__ __align__(16) __bf16 Ks[2][64 * 64];
  __shared__ __align__(16) __bf16 Vs[2][64 * 64];
  __shared__ float bias_s[2176];
  int tid = threadIdx.x, w = tid >> 6, l = tid & 63;
  int lr = l & 15, lh = l >> 4;
  int d = blockIdx.x;
  int bh = (d & 7) + ((d >> 3) & 3) * 8;
  int q0 = (d >> 5) * 128;
  int h = bh & 7, b = bh >> 3;
  const char* kbase = (const char*)(k + (size_t)bh * SEQ * 64);
  const char* vbase = (const char*)(vt + (size_t)bh * 64 * SEQ);

  // far-diagonal bias constants (bucket saturates at |d|>=91)
  float bR = bias_tab[h * 4096 + 2047 + 200];
  float bL = bias_tab[h * 4096 + 2047 - 200];

  for (int j = tid; j < 2176; j += 512)
    bias_s[j] = bias_tab[h * 4096 + (1920 - q0) + j];

  auto stageKV = [&](int kt, int buf) {
    const char* kb = kbase + (size_t)kt * 64 * 128;
    const char* vb = vbase + (size_t)kt * 128;
    int row = tid >> 3, colb = (tid & 7) * 16;
    gl_lds16(kb + row * 128 + (colb ^ swz(row)), (char*)&Ks[buf][0] + tid * 16);
    gl_lds16(vb + (size_t)row * 4096 + (colb ^ swz(row)), (char*)&Vs[buf][0] + tid * 16);
  };

  // Q fragments straight from global (per-lane 16B reads; no LDS round-trip)
  bf16x8 qfh[2], qfl[2];
  int qrow = w * 16 + lr;
  {
    const __bf16* qg = qhp + ((size_t)bh * SEQ + q0 + qrow) * 64;
    qfh[0] = *(const bf16x8*)(qg + lh * 8);
    qfh[1] = *(const bf16x8*)(qg + 32 + lh * 8);
    const __bf16* qg2 = qlp + ((size_t)bh * SEQ + q0 + qrow) * 64;
    qfl[0] = *(const bf16x8*)(qg2 + lh * 8);
    qfl[1] = *(const bf16x8*)(qg2 + 32 + lh * 8);
  }
  stageKV(0, 0);
  __syncthreads();

  // m_run: class-uniform running max (log2 domain). l_run: PER-LANE partial sum,
  // reduced once after the kt loop (sc rescales are class-uniform so partials stay consistent).
  float m_run = -1e30f, l_run = 0.f;
  f32x4 zero4 = {0.f, 0.f, 0.f, 0.f};
  f32x4 oacc[4];
#pragma unroll
  for (int i = 0; i < 4; ++i) oacc[i] = zero4;

#pragma unroll 2
  for (int kt = 0; kt < 32; ++kt) {
    int cur = kt & 1;
    if (kt + 1 < 32) stageKV(kt + 1, cur ^ 1);
    const char* kb = (const char*)&Ks[cur][0];
    f32x4 sacc[4];
    __builtin_amdgcn_s_setprio(1);
#pragma unroll
    for (int t = 0; t < 4; ++t) {
      int row = t * 16 + lr;
      bf16x8 b0 = *(const bf16x8*)(kb + row * 128 + ((lh * 16) ^ swz(row)));
      bf16x8 b1 = *(const bf16x8*)(kb + row * 128 + ((64 + lh * 16) ^ swz(row)));
      f32x4 z = zero4;
      z = __builtin_amdgcn_mfma_f32_16x16x32_bf16(b0, qfh[0], z, 0, 0, 0);
      z = __builtin_amdgcn_mfma_f32_16x16x32_bf16(b1, qfh[1], z, 0, 0, 0);
      z = __builtin_amdgcn_mfma_f32_16x16x32_bf16(b0, qfl[0], z, 0, 0, 0);
      z = __builtin_amdgcn_mfma_f32_16x16x32_bf16(b1, qfl[1], z, 0, 0, 0);
      sacc[t] = z;
    }
    __builtin_amdgcn_s_setprio(0);
    // lane (lr,lh) reg (t,r): S[q = q0+w*16+lr][k = kt*64 + t*16 + lh*4 + r]  (log2 domain)
    float p[4][4];
    float mx = -1e30f;
    int dmin = kt * 64 - q0 - 127, dmax = kt * 64 + 63 - q0;
    if (dmin >= 91 || dmax <= -91) {               // far tile: bias is per-head constant
      float cb = (dmin >= 91) ? bR : bL;
#pragma unroll
      for (int t = 0; t < 4; ++t)
#pragma unroll
        for (int r = 0; r < 4; ++r) {
          float sv = sacc[t][r] + cb;
          p[t][r] = sv;
          mx = fmaxf(mx, sv);
        }
    } else {                                       // diagonal band: per-element bias
      int jb = kt * 64 + lh * 4 + 127 - (w * 16 + lr);
#pragma unroll
      for (int t = 0; t < 4; ++t)
#pragma unroll
        for (int r = 0; r < 4; ++r) {
          float sv = sacc[t][r] + bias_s[jb + t * 16 + r];
          p[t][r] = sv;
          mx = fmaxf(mx, sv);
        }
    }
    // lazy defer-max: per-lane check is equivalent to class-reduced check under __all;
    // class max computed only when the (wave-uniform) rescale branch fires.
    if (!__all(mx <= m_run + 11.5f)) {
      mx = fmaxf(mx, __shfl_xor(mx, 16));
      mx = fmaxf(mx, __shfl_xor(mx, 32));
      float mnew = fmaxf(m_run, mx);
      float sc = fast_exp2(m_run - mnew);
      m_run = mnew;
      l_run *= sc;
#pragma unroll
      for (int r = 0; r < 4; ++r) {
        float scr = __shfl(sc, lh * 4 + r);        // sc of output row lh*4+r
#pragma unroll
        for (int ni = 0; ni < 4; ++ni) oacc[ni][r] *= scr;
      }
    }
    float rs = 0.f;
#pragma unroll
    for (int t = 0; t < 4; ++t)
#pragma unroll
      for (int r = 0; r < 4; ++r) {
        float pv = fast_exp2(p[t][r] - m_run);
        p[t][r] = pv;
        rs += pv;
      }
    l_run += rs;                                   // per-lane partial; no per-kt reduce
    // pack P in-register: pa0 slot(lh,e) holds k=16*(e/4)+4*lh+(e&3); V cols permuted to match
    uint32_t pk[4][2];
#pragma unroll
    for (int t = 0; t < 4; ++t) {
      asm("v_cvt_pk_bf16_f32 %0, %1, %2" : "=v"(pk[t][0]) : "v"(p[t][0]), "v"(p[t][1]));
      asm("v_cvt_pk_bf16_f32 %0, %1, %2" : "=v"(pk[t][1]) : "v"(p[t][2]), "v"(p[t][3]));
    }
    u32x4 A0 = {pk[0][0], pk[0][1], pk[1][0], pk[1][1]};
    u32x4 A1 = {pk[2][0], pk[2][1], pk[3][0], pk[3][1]};
    bf16x8 pa0 = __builtin_bit_cast(bf16x8, A0);
    bf16x8 pa1 = __builtin_bit_cast(bf16x8, A1);
    // PV
    {
      const char* vbr = (const char*)&Vs[cur][0];
      __builtin_amdgcn_s_setprio(1);
#pragma unroll
      for (int ni = 0; ni < 4; ++ni) {
        int vrow = ni * 16 + lr;
        bf16x8 v0 = *(const bf16x8*)(vbr + vrow * 128 + ((lh * 16) ^ swz(vrow)));
        bf16x8 v1 = *(const bf16x8*)(vbr + vrow * 128 + ((64 + lh * 16) ^ swz(vrow)));
        oacc[ni] = __builtin_amdgcn_mfma_f32_16x16x32_bf16(pa0, v0, oacc[ni], 0, 0, 0);
        oacc[ni] = __builtin_amdgcn_mfma_f32_16x16x32_bf16(pa1, v1, oacc[ni], 0, 0, 0);
      }
      __builtin_amdgcn_s_setprio(0);
    }
    __syncthreads();
  }

  // one-time class reduce of the per-lane l partials (butterfly over lanes ^16, ^32)
  l_run += __shfl_xor(l_run, 16);
  l_run += __shfl_xor(l_run, 32);

#pragma unroll
  for (int r = 0; r < 4; ++r) {
    float linv = 1.0f / __shfl(l_run, lh * 4 + r);
    int s = q0 + w * 16 + lh * 4 + r;
#pragma unroll
    for (int ni = 0; ni < 4; ++ni) {
      int dh = ni * 16 + lr;
      ao[((size_t)(b * 2048 + s)) * 512 + h * 64 + dh] = (__bf16)(oacc[ni][r] * linv);
    }
  }
}

extern "C" void kernel_launch(void* const* d_in, const int* in_sizes, int n_in,
                              void* d_out, int out_size, void* d_ws, size_t ws_size,
                              hipStream_t stream) {
  (void)in_sizes; (void)n_in; (void)out_size; (void)ws_size;
  const float* hs = (const float*)d_in[0];
  const float* Wq = (const float*)d_in[1];
  const float* Wk = (const float*)d_in[2];
  const float* Wv = (const float*)d_in[3];
  const float* Wo = (const float*)d_in[4];
  const float* rb = (const float*)d_in[5];
  char* ws = (char*)d_ws;
  __bf16* hs2    = (__bf16*)(ws + OFF_HS2);
  __bf16* wqkv2  = (__bf16*)(ws + OFF_WQKV2);
  __bf16* wo_t   = (__bf16*)(ws + OFF_WO);
  __bf16* qhb    = (__bf16*)(ws + OFF_QH);
  __bf16* qlb    = (__bf16*)(ws + OFF_QL);
  __bf16* kb     = (__bf16*)(ws + OFF_K);
  __bf16* vb     = (__bf16*)(ws + OFF_V);
  __bf16* vtb    = (__bf16*)(ws + OFF_VT);
  __bf16* aob    = (__bf16*)(ws + OFF_AO);
  float*  bias   = (float*)(ws + OFF_BIAS);

  k_cast_hs2<<<2048, 256, 0, stream>>>(hs, hs2);
  k_prep_w2<<<dim3(8, 8, 3), 256, 0, stream>>>(Wq, Wk, Wv, wqkv2);
  k_prep_wo<<<1024, 256, 0, stream>>>(Wo, wo_t);
  k_bias<<<128, 256, 0, stream>>>(rb, bias);
  k_gemm<0, 48, 1024, 1536><<<dim3(12, 64), 256, 0, stream>>>(hs2, wqkv2, qhb, qlb, kb, vb, nullptr);
  k_transv<<<dim3(32, 32), 256, 0, stream>>>(vb, vtb);
  k_attn<<<dim3(512), 512, 0, stream>>>(qhb, qlb, kb, vtb, bias, aob);
  k_gemm<1, 16, 512, 512><<<dim3(4, 64), 256, 0, stream>>>(aob, wo_t, nullptr, nullptr, nullptr, nullptr, (float*)d_out);
}

// Round 13
// 136.515 us; speedup vs baseline: 1.2049x; 1.0365x over previous
//
#include <hip/hip_runtime.h>
#include <stdint.h>

typedef __attribute__((ext_vector_type(8))) __bf16 bf16x8;
typedef __attribute__((ext_vector_type(4))) __bf16 bf16x4;
typedef __attribute__((ext_vector_type(4))) float f32x4;
typedef __attribute__((ext_vector_type(4))) unsigned int u32x4;

#define SEQ 2048
#define LOG2E 1.4426950408889634f

// ---------- ws layout (bytes) ----------
#define OFF_HS2   0ull               // bf16 [8192][1024]  ([hi|lo] along K)
#define OFF_VT    0ull               // bf16 [32][64][2048]   (overlay, after GEMM; k-permuted cols)
#define OFF_AO    8388608ull         // bf16 [8192][512]      (overlay, after GEMM)
#define OFF_WQKV2 16777216ull        // bf16 [1536][1536]  (w_t[n][k'], k'=[hi|hi|lo]; Wq pre-scaled by log2e)
#define OFF_WO    21495808ull        // bf16 [512][512]
#define OFF_QH    22020096ull        // bf16 [32][2048][64]
#define OFF_QL    30408704ull
#define OFF_K     38797312ull
#define OFF_V     47185920ull
#define OFF_BIAS  55574528ull        // f32 [8][4096]  (scaled by log2e)

__device__ __forceinline__ int swz(int row) { return ((row & 7) << 4) ^ ((row & 8) << 1); }

__device__ __forceinline__ void gl_lds16(const void* g, void* l) {
  __builtin_amdgcn_global_load_lds(
      (__attribute__((address_space(1))) void*)(uintptr_t)g,
      (__attribute__((address_space(3))) void*)(uint32_t)(uintptr_t)l, 16, 0, 0);
}

// raw v_exp_f32 (2^x), 1-ulp hardware transcendental
__device__ __forceinline__ float fast_exp2(float x) { return __builtin_amdgcn_exp2f(x); }

// ---------- prep: hidden_states f32 -> [hi|lo] bf16, K' = 1024 (read once) ----------
__global__ void k_cast_hs2(const float* __restrict__ hs, __bf16* __restrict__ out) {
  int gid = blockIdx.x * 256 + threadIdx.x;       // 524288
  int row = gid >> 6, c8 = (gid & 63) * 8;
  const float* p = hs + (size_t)row * 512 + c8;
  float4 a = *(const float4*)p, b = *(const float4*)(p + 4);
  float v[8] = {a.x, a.y, a.z, a.w, b.x, b.y, b.z, b.w};
  bf16x8 hi, lo;
#pragma unroll
  for (int j = 0; j < 8; ++j) {
    __bf16 h = (__bf16)v[j];
    hi[j] = h;
    lo[j] = (__bf16)(v[j] - (float)h);
  }
  *(bf16x8*)(out + (size_t)row * 1024 + c8) = hi;
  *(bf16x8*)(out + (size_t)row * 1024 + 512 + c8) = lo;
}

// ---------- prep: QKV weights (z<3, split+log2e) / Wo transpose + bias table (z==3) ----------
__global__ void k_prep_w2(const float* __restrict__ Wq, const float* __restrict__ Wk,
                          const float* __restrict__ Wv, const float* __restrict__ Wo,
                          const float* __restrict__ rel_bias,
                          __bf16* __restrict__ w2, __bf16* __restrict__ wo_t,
                          float* __restrict__ bias_tab) {
  __shared__ float tile[64][65];
  int z = blockIdx.z;
  const float* W = (z == 0) ? Wq : (z == 1) ? Wk : (z == 2) ? Wv : Wo;
  int k0 = blockIdx.y * 64, n0 = blockIdx.x * 64;
  int tx = threadIdx.x & 63, ty = threadIdx.x >> 6;
  for (int r = ty; r < 64; r += 4) tile[r][tx] = W[(size_t)(k0 + r) * 512 + n0 + tx];
  __syncthreads();
  if (z < 3) {
    float scale = (z == 0) ? LOG2E : 1.0f;
    for (int r = ty; r < 64; r += 4) {
      float v = tile[tx][r] * scale;             // (k=k0+tx, n=n0+r)
      __bf16 h = (__bf16)v;
      __bf16 lo = (__bf16)(v - (float)h);
      __bf16* dst = w2 + (size_t)(z * 512 + n0 + r) * 1536;
      dst[k0 + tx] = h;
      dst[512 + k0 + tx] = h;
      dst[1024 + k0 + tx] = lo;
    }
  } else {
    for (int r = ty; r < 64; r += 4)
      wo_t[(size_t)(n0 + r) * 512 + k0 + tx] = (__bf16)tile[tx][r];
    // bias table: 64 z==3 blocks x 512 elements = 8*4096
    int blk = blockIdx.y * 8 + blockIdx.x;
#pragma unroll
    for (int e = 0; e < 2; ++e) {
      int idx = blk * 512 + e * 256 + threadIdx.x;
      int h = idx >> 12, dIdx = idx & 4095;
      float v = 0.f;
      if (dIdx < 4095) {
        int d = dIdx - 2047;
        int rp = d < 0 ? -d : d;
        int bp;
        if (rp < 8) bp = rp;
        else bp = 8 + (rp >= 12) + (rp >= 16) + (rp >= 23) + (rp >= 32) + (rp >= 46) + (rp >= 64) + (rp >= 91);
        v = rel_bias[((d > 0 ? 16 : 0) + bp) * 8 + h] * LOG2E;
      }
      bias_tab[idx] = v;
    }
  }
}

// ---------- GEMM; MODE 0: QKV split (Q 48, K 32, V 16 K-steps); XCD-swizzled grid ----------
template <int MODE, int KSTEPS, int LDA, int LDB>
__global__ __launch_bounds__(256) void k_gemm(const __bf16* __restrict__ A,
                                              const __bf16* __restrict__ Bt,
                                              __bf16* __restrict__ qh, __bf16* __restrict__ ql,
                                              __bf16* __restrict__ ko, __bf16* __restrict__ vo,
                                              float* __restrict__ fo) {
  __shared__ __align__(16) __bf16 As[2][128 * 32];
  __shared__ __align__(16) __bf16 Bs[2][128 * 32];
  int tid = threadIdx.x, w = tid >> 6, l = tid & 63;
  int lr = l & 15, lh = l >> 4;
  // XCD-aware bijective remap (nwg % 8 == 0 for both modes)
  int nwg = gridDim.x * gridDim.y;
  int flat = blockIdx.y * gridDim.x + blockIdx.x;
  int flat2 = (flat & 7) * (nwg >> 3) + (flat >> 3);
  int m0 = (flat2 / gridDim.x) * 128, n0 = (flat2 % gridDim.x) * 128;
  int wm = (w >> 1) * 64, wn = (w & 1) * 64;
  int ksteps = (MODE == 0) ? (n0 >= 1024 ? 16 : (n0 >= 512 ? 32 : 48)) : KSTEPS;
  f32x4 zero4 = {0.f, 0.f, 0.f, 0.f};
  f32x4 acc[4][4];
#pragma unroll
  for (int i = 0; i < 4; ++i)
#pragma unroll
    for (int j = 0; j < 4; ++j) acc[i][j] = zero4;

  auto stage = [&](int kt, int buf) {
    int ka = (MODE == 0 && kt >= 32) ? kt - 32 : kt;
#pragma unroll
    for (int c = 0; c < 2; ++c) {
      int i = c * 256 + w * 64 + l;
      int row = i >> 2, cc = i & 3;
      gl_lds16(A + (size_t)(m0 + row) * LDA + ka * 32 + cc * 8,
               (char*)&As[buf][0] + (c * 256 + w * 64) * 16);
      gl_lds16(Bt + (size_t)(n0 + row) * LDB + kt * 32 + cc * 8,
               (char*)&Bs[buf][0] + (c * 256 + w * 64) * 16);
    }
  };

  stage(0, 0);
  __syncthreads();
  int cur = 0;
  for (int kt = 0; kt < ksteps; ++kt) {
    if (kt + 1 < ksteps) stage(kt + 1, cur ^ 1);
    bf16x8 af[4], bfr[4];
#pragma unroll
    for (int mi = 0; mi < 4; ++mi)
      af[mi] = *(const bf16x8*)&As[cur][(wm + mi * 16 + lr) * 32 + lh * 8];
#pragma unroll
    for (int ni = 0; ni < 4; ++ni)
      bfr[ni] = *(const bf16x8*)&Bs[cur][(wn + ni * 16 + lr) * 32 + lh * 8];
#pragma unroll
    for (int mi = 0; mi < 4; ++mi)
#pragma unroll
      for (int ni = 0; ni < 4; ++ni)
        acc[mi][ni] = __builtin_amdgcn_mfma_f32_16x16x32_bf16(af[mi], bfr[ni], acc[mi][ni], 0, 0, 0);
    __syncthreads();
    cur ^= 1;
  }

#pragma unroll
  for (int mi = 0; mi < 4; ++mi)
#pragma unroll
    for (int ni = 0; ni < 4; ++ni)
#pragma unroll
      for (int r = 0; r < 4; ++r) {
        int m = m0 + wm + mi * 16 + lh * 4 + r;
        int n = n0 + wn + ni * 16 + lr;
        float vv = acc[mi][ni][r];
        if (MODE == 0) {
          int which = n >> 9, c9 = n & 511, hh = c9 >> 6, dh = c9 & 63;
          int b = m >> 11, s = m & 2047;
          size_t o = (size_t)((b * 8 + hh) * 2048 + s) * 64 + dh;
          if (which == 0) {
            __bf16 hv = (__bf16)vv;
            qh[o] = hv;
            ql[o] = (__bf16)(vv - (float)hv);
          } else if (which == 1) {
            ko[o] = (__bf16)vv;
          } else {
            vo[o] = (__bf16)vv;
          }
        } else {
          fo[(size_t)m * 512 + n] = vv;
        }
      }
}

// ---------- transpose V to [bh][dh][s], with per-64 k-column permutation ----------
__global__ void k_transv(const __bf16* __restrict__ v, __bf16* __restrict__ vt) {
  __shared__ __bf16 t[64][72];
  int bh = blockIdx.y, s0 = blockIdx.x * 64, tid = threadIdx.x;
  const __bf16* src = v + (size_t)bh * SEQ * 64;
  __bf16* dst = vt + (size_t)bh * 64 * SEQ;
#pragma unroll
  for (int c = 0; c < 2; ++c) {
    int i = c * 256 + tid, row = i >> 3, col = (i & 7) * 8;
    *(bf16x8*)&t[row][col] = *(const bf16x8*)&src[(size_t)(s0 + row) * 64 + col];
  }
  __syncthreads();
#pragma unroll
  for (int c = 0; c < 2; ++c) {
    int i = c * 256 + tid, dh = i >> 3, c8 = i & 7;
    bf16x4 o1, o2;
#pragma unroll
    for (int j = 0; j < 4; ++j) { o1[j] = t[c8 * 8 + j][dh]; o2[j] = t[c8 * 8 + 4 + j][dh]; }
    int c2a = 2 * c8, c2b = 2 * c8 + 1;
    int d2a = ((c2a >> 3) << 3) | ((c2a & 3) << 1) | ((c2a >> 2) & 1);
    int d2b = ((c2b >> 3) << 3) | ((c2b & 3) << 1) | ((c2b >> 2) & 1);
    *(bf16x4*)&dst[(size_t)dh * SEQ + s0 + 4 * d2a] = o1;
    *(bf16x4*)&dst[(size_t)dh * SEQ + s0 + 4 * d2b] = o2;
  }
}

// ---------- flash attention: swapped QK^T, register P, 4-buffer KV, far-tile fold ----------
__global__ __launch_bounds__(512) void k_attn(const __bf16* __restrict__ qhp,
                                              const __bf16* __restrict__ qlp,
                                              const __bf16* __restrict__ k,
                                              const __bf16* __restrict__ vt,
                                              const float* __restrict__ bias_tab,
                                              __bf16* __restrict__ ao) {
  __shared__ __align__(16) __bf16 Ks[4][64 * 64];
  __shared__ __align__(16) __bf16 Vs[4][64 * 64];
  __shared__ float bias_s[2176];
  int tid = threadIdx.x, w = tid >> 6, l = tid & 63;
  int lr = l & 15, lh = l >> 4;
  int d = blockIdx.x;
  int bh = (d & 7) + ((d >> 3) & 3) * 8;
  int q0 = (d >> 5) * 128;
  int h = bh & 7, b = bh >> 3;
  const char* kbase = (const char*)(k + (size_t)bh * SEQ * 64);
  const char* vbase = (const char*)(vt + (size_t)bh * 64 * SEQ);

  float bR = bias_tab[h * 4096 + 2047 + 200];
  float bL = bias_tab[h * 4096 + 2047 - 200];

  for (int j = tid; j < 2176; j += 512)
    bias_s[j] = bias_tab[h * 4096 + (1920 - q0) + j];

  auto stageKV = [&](int kt, int buf) {
    const char* kb = kbase + (size_t)kt * 64 * 128;
    const char* vb = vbase + (size_t)kt * 128;
    int row = tid >> 3, colb = (tid & 7) * 16;
    gl_lds16(kb + row * 128 + (colb ^ swz(row)), (char*)&Ks[buf][0] + tid * 16);
    gl_lds16(vb + (size_t)row * 4096 + (colb ^ swz(row)), (char*)&Vs[buf][0] + tid * 16);
  };

  // Q fragments straight from global
  bf16x8 qfh[2], qfl[2];
  int qrow = w * 16 + lr;
  {
    const __bf16* qg = qhp + ((size_t)bh * SEQ + q0 + qrow) * 64;
    qfh[0] = *(const bf16x8*)(qg + lh * 8);
    qfh[1] = *(const bf16x8*)(qg + 32 + lh * 8);
    const __bf16* qg2 = qlp + ((size_t)bh * SEQ + q0 + qrow) * 64;
    qfl[0] = *(const bf16x8*)(qg2 + lh * 8);
    qfl[1] = *(const bf16x8*)(qg2 + 32 + lh * 8);
  }

  float m_run = -1e30f, l_run = 0.f;
  f32x4 zero4 = {0.f, 0.f, 0.f, 0.f};
  f32x4 oacc[4];
#pragma unroll
  for (int i = 0; i < 4; ++i) oacc[i] = zero4;

  auto compute = [&](int kt, int buf) {
    const char* kb = (const char*)&Ks[buf][0];
    f32x4 sacc[4];
    __builtin_amdgcn_s_setprio(1);
#pragma unroll
    for (int t = 0; t < 4; ++t) {
      int row = t * 16 + lr;
      bf16x8 b0 = *(const bf16x8*)(kb + row * 128 + ((lh * 16) ^ swz(row)));
      bf16x8 b1 = *(const bf16x8*)(kb + row * 128 + ((64 + lh * 16) ^ swz(row)));
      f32x4 z = zero4;
      z = __builtin_amdgcn_mfma_f32_16x16x32_bf16(b0, qfh[0], z, 0, 0, 0);
      z = __builtin_amdgcn_mfma_f32_16x16x32_bf16(b1, qfh[1], z, 0, 0, 0);
      z = __builtin_amdgcn_mfma_f32_16x16x32_bf16(b0, qfl[0], z, 0, 0, 0);
      z = __builtin_amdgcn_mfma_f32_16x16x32_bf16(b1, qfl[1], z, 0, 0, 0);
      sacc[t] = z;
    }
    __builtin_amdgcn_s_setprio(0);
    // effective-coordinate softmax: far tiles fold constant bias into the max shift
    float p[4][4];
    float mx = -1e30f;
    int dmin = kt * 64 - q0 - 127, dmax = kt * 64 + 63 - q0;
    bool far = (dmin >= 91) || (dmax <= -91);
    float cb = far ? ((dmin >= 91) ? bR : bL) : 0.f;
    if (far) {
#pragma unroll
      for (int t = 0; t < 4; ++t)
#pragma unroll
        for (int r = 0; r < 4; ++r) {
          float sv = sacc[t][r];
          p[t][r] = sv;
          mx = fmaxf(mx, sv);
        }
    } else {
      int jb = kt * 64 + lh * 4 + 127 - (w * 16 + lr);
#pragma unroll
      for (int t = 0; t < 4; ++t)
#pragma unroll
        for (int r = 0; r < 4; ++r) {
          float sv = sacc[t][r] + bias_s[jb + t * 16 + r];
          p[t][r] = sv;
          mx = fmaxf(mx, sv);
        }
    }
    float me = m_run - cb;                       // effective running max for this tile
    if (!__all(mx <= me + 11.5f)) {
      mx = fmaxf(mx, __shfl_xor(mx, 16));
      mx = fmaxf(mx, __shfl_xor(mx, 32));
      float men = fmaxf(me, mx);
      float sc = fast_exp2(me - men);
      m_run = men + cb;
      me = men;
      l_run *= sc;
#pragma unroll
      for (int r = 0; r < 4; ++r) {
        float scr = __shfl(sc, lh * 4 + r);
#pragma unroll
        for (int ni = 0; ni < 4; ++ni) oacc[ni][r] *= scr;
      }
    }
    float rs = 0.f;
#pragma unroll
    for (int t = 0; t < 4; ++t)
#pragma unroll
      for (int r = 0; r < 4; ++r) {
        float pv = fast_exp2(p[t][r] - me);
        p[t][r] = pv;
        rs += pv;
      }
    l_run += rs;                                 // per-lane partial
    uint32_t pk[4][2];
#pragma unroll
    for (int t = 0; t < 4; ++t) {
      asm("v_cvt_pk_bf16_f32 %0, %1, %2" : "=v"(pk[t][0]) : "v"(p[t][0]), "v"(p[t][1]));
      asm("v_cvt_pk_bf16_f32 %0, %1, %2" : "=v"(pk[t][1]) : "v"(p[t][2]), "v"(p[t][3]));
    }
    u32x4 A0 = {pk[0][0], pk[0][1], pk[1][0], pk[1][1]};
    u32x4 A1 = {pk[2][0], pk[2][1], pk[3][0], pk[3][1]};
    bf16x8 pa0 = __builtin_bit_cast(bf16x8, A0);
    bf16x8 pa1 = __builtin_bit_cast(bf16x8, A1);
    const char* vbr = (const char*)&Vs[buf][0];
    __builtin_amdgcn_s_setprio(1);
#pragma unroll
    for (int ni = 0; ni < 4; ++ni) {
      int vrow = ni * 16 + lr;
      bf16x8 v0 = *(const bf16x8*)(vbr + vrow * 128 + ((lh * 16) ^ swz(vrow)));
      bf16x8 v1 = *(const bf16x8*)(vbr + vrow * 128 + ((64 + lh * 16) ^ swz(vrow)));
      oacc[ni] = __builtin_amdgcn_mfma_f32_16x16x32_bf16(pa0, v0, oacc[ni], 0, 0, 0);
      oacc[ni] = __builtin_amdgcn_mfma_f32_16x16x32_bf16(pa1, v1, oacc[ni], 0, 0, 0);
    }
    __builtin_amdgcn_s_setprio(0);
  };

  // 4-buffer pipeline: one barrier per 2 kt
  stageKV(0, 0);
  stageKV(1, 1);
  __syncthreads();
  for (int kp = 0; kp < 16; ++kp) {
    int rb_ = (kp & 1) * 2;                      // read pair {rb_, rb_+1}
    if (kp < 15) {
      stageKV(2 * kp + 2, rb_ ^ 2);
      stageKV(2 * kp + 3, (rb_ ^ 2) + 1);
    }
    compute(2 * kp, rb_);
    compute(2 * kp + 1, rb_ + 1);
    __syncthreads();
  }

  // one-time class reduce of per-lane l partials
  l_run += __shfl_xor(l_run, 16);
  l_run += __shfl_xor(l_run, 32);

#pragma unroll
  for (int r = 0; r < 4; ++r) {
    float linv = 1.0f / __shfl(l_run, lh * 4 + r);
    int s = q0 + w * 16 + lh * 4 + r;
#pragma unroll
    for (int ni = 0; ni < 4; ++ni) {
      int dh = ni * 16 + lr;
      ao[((size_t)(b * 2048 + s)) * 512 + h * 64 + dh] = (__bf16)(oacc[ni][r] * linv);
    }
  }
}

extern "C" void kernel_launch(void* const* d_in, const int* in_sizes, int n_in,
                              void* d_out, int out_size, void* d_ws, size_t ws_size,
                              hipStream_t stream) {
  (void)in_sizes; (void)n_in; (void)out_size; (void)ws_size;
  const float* hs = (const float*)d_in[0];
  const float* Wq = (const float*)d_in[1];
  const float* Wk = (const float*)d_in[2];
  const float* Wv = (const float*)d_in[3];
  const float* Wo = (const float*)d_in[4];
  const float* rb = (const float*)d_in[5];
  char* ws = (char*)d_ws;
  __bf16* hs2    = (__bf16*)(ws + OFF_HS2);
  __bf16* wqkv2  = (__bf16*)(ws + OFF_WQKV2);
  __bf16* wo_t   = (__bf16*)(ws + OFF_WO);
  __bf16* qhb    = (__bf16*)(ws + OFF_QH);
  __bf16* qlb    = (__bf16*)(ws + OFF_QL);
  __bf16* kb     = (__bf16*)(ws + OFF_K);
  __bf16* vb     = (__bf16*)(ws + OFF_V);
  __bf16* vtb    = (__bf16*)(ws + OFF_VT);
  __bf16* aob    = (__bf16*)(ws + OFF_AO);
  float*  bias   = (float*)(ws + OFF_BIAS);

  k_cast_hs2<<<2048, 256, 0, stream>>>(hs, hs2);
  k_prep_w2<<<dim3(8, 8, 4), 256, 0, stream>>>(Wq, Wk, Wv, Wo, rb, wqkv2, wo_t, bias);
  k_gemm<0, 48, 1024, 1536><<<dim3(12, 64), 256, 0, stream>>>(hs2, wqkv2, qhb, qlb, kb, vb, nullptr);
  k_transv<<<dim3(32, 32), 256, 0, stream>>>(vb, vtb);
  k_attn<<<dim3(512), 512, 0, stream>>>(qhb, qlb, kb, vtb, bias, aob);
  k_gemm<1, 16, 512, 512><<<dim3(4, 64), 256, 0, stream>>>(aob, wo_t, nullptr, nullptr, nullptr, nullptr, (float*)d_out);
}

// Round 14
// 124.515 us; speedup vs baseline: 1.3210x; 1.0964x over previous
//
#include <hip/hip_runtime.h>
#include <stdint.h>

typedef __attribute__((ext_vector_type(8))) __bf16 bf16x8;
typedef __attribute__((ext_vector_type(4))) __bf16 bf16x4;
typedef __attribute__((ext_vector_type(4))) float f32x4;
typedef __attribute__((ext_vector_type(4))) unsigned int u32x4;

#define SEQ 2048
#define LOG2E 1.4426950408889634f

// ---------- ws layout (bytes) ----------
#define OFF_HS2   0ull               // bf16 [8192][1024]  ([hi|lo] along K)
#define OFF_AO    8388608ull         // bf16 [8192][512]      (overlay, after GEMM)
#define OFF_WQKV2 16777216ull        // bf16 [1536][1536]  (w_t[n][k'], k'=[hi|hi|lo]; Wq pre-scaled by log2e)
#define OFF_WO    21495808ull        // bf16 [512][512]
#define OFF_QH    22020096ull        // bf16 [32][2048][64]
#define OFF_QL    30408704ull
#define OFF_K     38797312ull
#define OFF_VT    47185920ull        // bf16 [32][64][2048]  (written directly by GEMM epilogue, s-permuted)
#define OFF_BIAS  55574528ull        // f32 [8][4096]  (scaled by log2e)

__device__ __forceinline__ int swz(int row) { return ((row & 7) << 4) ^ ((row & 8) << 1); }

__device__ __forceinline__ void gl_lds16(const void* g, void* l) {
  __builtin_amdgcn_global_load_lds(
      (__attribute__((address_space(1))) void*)(uintptr_t)g,
      (__attribute__((address_space(3))) void*)(uint32_t)(uintptr_t)l, 16, 0, 0);
}

// raw v_exp_f32 (2^x), 1-ulp hardware transcendental
__device__ __forceinline__ float fast_exp2(float x) { return __builtin_amdgcn_exp2f(x); }

// ---------- prep: weights (z<3 split QKV / z==3 Wo+bias) and hs cast (z>=4) ----------
__global__ void k_prep(const float* __restrict__ hs,
                       const float* __restrict__ Wq, const float* __restrict__ Wk,
                       const float* __restrict__ Wv, const float* __restrict__ Wo,
                       const float* __restrict__ rel_bias,
                       __bf16* __restrict__ hs2, __bf16* __restrict__ w2,
                       __bf16* __restrict__ wo_t, float* __restrict__ bias_tab) {
  int z = blockIdx.z;
  if (z >= 4) {
    // hidden_states f32 -> [hi|lo] bf16, 2048 virtual blocks
    int cid = (z - 4) * 64 + blockIdx.y * 8 + blockIdx.x;
    int gid = cid * 256 + threadIdx.x;
    int row = gid >> 6, c8 = (gid & 63) * 8;
    const float* p = hs + (size_t)row * 512 + c8;
    float4 a = *(const float4*)p, b = *(const float4*)(p + 4);
    float v[8] = {a.x, a.y, a.z, a.w, b.x, b.y, b.z, b.w};
    bf16x8 hi, lo;
#pragma unroll
    for (int j = 0; j < 8; ++j) {
      __bf16 h = (__bf16)v[j];
      hi[j] = h;
      lo[j] = (__bf16)(v[j] - (float)h);
    }
    *(bf16x8*)(hs2 + (size_t)row * 1024 + c8) = hi;
    *(bf16x8*)(hs2 + (size_t)row * 1024 + 512 + c8) = lo;
    return;
  }
  __shared__ float tile[64][65];
  const float* W = (z == 0) ? Wq : (z == 1) ? Wk : (z == 2) ? Wv : Wo;
  int k0 = blockIdx.y * 64, n0 = blockIdx.x * 64;
  int tx = threadIdx.x & 63, ty = threadIdx.x >> 6;
  for (int r = ty; r < 64; r += 4) tile[r][tx] = W[(size_t)(k0 + r) * 512 + n0 + tx];
  __syncthreads();
  if (z < 3) {
    float scale = (z == 0) ? LOG2E : 1.0f;
    for (int r = ty; r < 64; r += 4) {
      float v = tile[tx][r] * scale;             // (k=k0+tx, n=n0+r)
      __bf16 h = (__bf16)v;
      __bf16 lo = (__bf16)(v - (float)h);
      __bf16* dst = w2 + (size_t)(z * 512 + n0 + r) * 1536;
      dst[k0 + tx] = h;
      dst[512 + k0 + tx] = h;
      dst[1024 + k0 + tx] = lo;
    }
  } else {
    for (int r = ty; r < 64; r += 4)
      wo_t[(size_t)(n0 + r) * 512 + k0 + tx] = (__bf16)tile[tx][r];
    int blk = blockIdx.y * 8 + blockIdx.x;
#pragma unroll
    for (int e = 0; e < 2; ++e) {
      int idx = blk * 512 + e * 256 + threadIdx.x;
      int h = idx >> 12, dIdx = idx & 4095;
      float v = 0.f;
      if (dIdx < 4095) {
        int d = dIdx - 2047;
        int rp = d < 0 ? -d : d;
        int bp;
        if (rp < 8) bp = rp;
        else bp = 8 + (rp >= 12) + (rp >= 16) + (rp >= 23) + (rp >= 32) + (rp >= 46) + (rp >= 64) + (rp >= 91);
        v = rel_bias[((d > 0 ? 16 : 0) + bp) * 8 + h] * LOG2E;
      }
      bias_tab[idx] = v;
    }
  }
}

// ---------- GEMM; MODE 0: QKV split (Q 48, K 32, V 16 K-steps); V writes vt directly ----------
template <int MODE, int KSTEPS, int LDA, int LDB>
__global__ __launch_bounds__(256) void k_gemm(const __bf16* __restrict__ A,
                                              const __bf16* __restrict__ Bt,
                                              __bf16* __restrict__ qh, __bf16* __restrict__ ql,
                                              __bf16* __restrict__ ko, __bf16* __restrict__ vt,
                                              float* __restrict__ fo) {
  __shared__ __align__(16) __bf16 As[2][128 * 32];
  __shared__ __align__(16) __bf16 Bs[2][128 * 32];
  int tid = threadIdx.x, w = tid >> 6, l = tid & 63;
  int lr = l & 15, lh = l >> 4;
  // XCD-aware bijective remap (nwg % 8 == 0 for both modes)
  int nwg = gridDim.x * gridDim.y;
  int flat = blockIdx.y * gridDim.x + blockIdx.x;
  int flat2 = (flat & 7) * (nwg >> 3) + (flat >> 3);
  int m0 = (flat2 / gridDim.x) * 128, n0 = (flat2 % gridDim.x) * 128;
  int wm = (w >> 1) * 64, wn = (w & 1) * 64;
  int ksteps = (MODE == 0) ? (n0 >= 1024 ? 16 : (n0 >= 512 ? 32 : 48)) : KSTEPS;
  f32x4 zero4 = {0.f, 0.f, 0.f, 0.f};
  f32x4 acc[4][4];
#pragma unroll
  for (int i = 0; i < 4; ++i)
#pragma unroll
    for (int j = 0; j < 4; ++j) acc[i][j] = zero4;

  auto stage = [&](int kt, int buf) {
    int ka = (MODE == 0 && kt >= 32) ? kt - 32 : kt;
#pragma unroll
    for (int c = 0; c < 2; ++c) {
      int i = c * 256 + w * 64 + l;
      int row = i >> 2, cc = i & 3;
      gl_lds16(A + (size_t)(m0 + row) * LDA + ka * 32 + cc * 8,
               (char*)&As[buf][0] + (c * 256 + w * 64) * 16);
      gl_lds16(Bt + (size_t)(n0 + row) * LDB + kt * 32 + cc * 8,
               (char*)&Bs[buf][0] + (c * 256 + w * 64) * 16);
    }
  };

  stage(0, 0);
  __syncthreads();
  int cur = 0;
  for (int kt = 0; kt < ksteps; ++kt) {
    if (kt + 1 < ksteps) stage(kt + 1, cur ^ 1);
    bf16x8 af[4], bfr[4];
#pragma unroll
    for (int mi = 0; mi < 4; ++mi)
      af[mi] = *(const bf16x8*)&As[cur][(wm + mi * 16 + lr) * 32 + lh * 8];
#pragma unroll
    for (int ni = 0; ni < 4; ++ni)
      bfr[ni] = *(const bf16x8*)&Bs[cur][(wn + ni * 16 + lr) * 32 + lh * 8];
#pragma unroll
    for (int mi = 0; mi < 4; ++mi)
#pragma unroll
      for (int ni = 0; ni < 4; ++ni)
        acc[mi][ni] = __builtin_amdgcn_mfma_f32_16x16x32_bf16(af[mi], bfr[ni], acc[mi][ni], 0, 0, 0);
    __syncthreads();
    cur ^= 1;
  }

  if (MODE == 0 && n0 >= 1024) {
    // V epilogue: write transposed + s-permuted directly into vt[bh][dh][s']
#pragma unroll
    for (int mi = 0; mi < 4; ++mi)
#pragma unroll
      for (int ni = 0; ni < 4; ++ni) {
        int m = m0 + wm + mi * 16 + lh * 4;
        int n = n0 + wn + ni * 16 + lr;
        int c9 = n & 511, hh = c9 >> 6, dh = c9 & 63;
        int b = m >> 11, s = m & 2047;
        int loc = s & 63;
        int pp = ((loc >> 5) << 5) | (((loc >> 2) & 3) << 3) | (((loc >> 4) & 1) << 2);
        bf16x4 o;
#pragma unroll
        for (int r = 0; r < 4; ++r) o[r] = (__bf16)acc[mi][ni][r];
        *(bf16x4*)&vt[((size_t)(b * 8 + hh) * 64 + dh) * 2048 + (s & ~63) + pp] = o;
      }
    return;
  }

#pragma unroll
  for (int mi = 0; mi < 4; ++mi)
#pragma unroll
    for (int ni = 0; ni < 4; ++ni)
#pragma unroll
      for (int r = 0; r < 4; ++r) {
        int m = m0 + wm + mi * 16 + lh * 4 + r;
        int n = n0 + wn + ni * 16 + lr;
        float vv = acc[mi][ni][r];
        if (MODE == 0) {
          int which = n >> 9, c9 = n & 511, hh = c9 >> 6, dh = c9 & 63;
          int b = m >> 11, s = m & 2047;
          size_t o = (size_t)((b * 8 + hh) * 2048 + s) * 64 + dh;
          if (which == 0) {
            __bf16 hv = (__bf16)vv;
            qh[o] = hv;
            ql[o] = (__bf16)(vv - (float)hv);
          } else {
            ko[o] = (__bf16)vv;
          }
        } else {
          fo[(size_t)m * 512 + n] = vv;
        }
      }
}

// ---------- flash attention: swapped QK^T, register P, 4-buffer KV, counted vmcnt ----------
__global__ __launch_bounds__(512) void k_attn(const __bf16* __restrict__ qhp,
                                              const __bf16* __restrict__ qlp,
                                              const __bf16* __restrict__ k,
                                              const __bf16* __restrict__ vt,
                                              const float* __restrict__ bias_tab,
                                              __bf16* __restrict__ ao) {
  __shared__ __align__(16) __bf16 Ks[4][64 * 64];
  __shared__ __align__(16) __bf16 Vs[4][64 * 64];
  __shared__ float bias_s[2176];
  int tid = threadIdx.x, w = tid >> 6, l = tid & 63;
  int lr = l & 15, lh = l >> 4;
  int d = blockIdx.x;
  int bh = (d & 7) + ((d >> 3) & 3) * 8;
  int q0 = (d >> 5) * 128;
  int h = bh & 7, b = bh >> 3;
  const char* kbase = (const char*)(k + (size_t)bh * SEQ * 64);
  const char* vbase = (const char*)(vt + (size_t)bh * 64 * SEQ);

  float bR = bias_tab[h * 4096 + 2047 + 200];
  float bL = bias_tab[h * 4096 + 2047 - 200];

  for (int j = tid; j < 2176; j += 512)
    bias_s[j] = bias_tab[h * 4096 + (1920 - q0) + j];

  auto stageKV = [&](int kt, int buf) {
    const char* kb = kbase + (size_t)kt * 64 * 128;
    const char* vb = vbase + (size_t)kt * 128;
    int row = tid >> 3, colb = (tid & 7) * 16;
    gl_lds16(kb + row * 128 + (colb ^ swz(row)), (char*)&Ks[buf][0] + tid * 16);
    gl_lds16(vb + (size_t)row * 4096 + (colb ^ swz(row)), (char*)&Vs[buf][0] + tid * 16);
  };

  // Q fragments straight from global
  bf16x8 qfh[2], qfl[2];
  int qrow = w * 16 + lr;
  {
    const __bf16* qg = qhp + ((size_t)bh * SEQ + q0 + qrow) * 64;
    qfh[0] = *(const bf16x8*)(qg + lh * 8);
    qfh[1] = *(const bf16x8*)(qg + 32 + lh * 8);
    const __bf16* qg2 = qlp + ((size_t)bh * SEQ + q0 + qrow) * 64;
    qfl[0] = *(const bf16x8*)(qg2 + lh * 8);
    qfl[1] = *(const bf16x8*)(qg2 + 32 + lh * 8);
  }

  float m_run = -1e30f, l_run = 0.f;
  f32x4 zero4 = {0.f, 0.f, 0.f, 0.f};
  f32x4 oacc[4];
#pragma unroll
  for (int i = 0; i < 4; ++i) oacc[i] = zero4;

  auto compute = [&](int kt, int buf) {
    const char* kb = (const char*)&Ks[buf][0];
    f32x4 sacc[4];
    __builtin_amdgcn_s_setprio(1);
#pragma unroll
    for (int t = 0; t < 4; ++t) {
      int row = t * 16 + lr;
      bf16x8 b0 = *(const bf16x8*)(kb + row * 128 + ((lh * 16) ^ swz(row)));
      bf16x8 b1 = *(const bf16x8*)(kb + row * 128 + ((64 + lh * 16) ^ swz(row)));
      f32x4 z = zero4;
      z = __builtin_amdgcn_mfma_f32_16x16x32_bf16(b0, qfh[0], z, 0, 0, 0);
      z = __builtin_amdgcn_mfma_f32_16x16x32_bf16(b1, qfh[1], z, 0, 0, 0);
      z = __builtin_amdgcn_mfma_f32_16x16x32_bf16(b0, qfl[0], z, 0, 0, 0);
      z = __builtin_amdgcn_mfma_f32_16x16x32_bf16(b1, qfl[1], z, 0, 0, 0);
      sacc[t] = z;
    }
    __builtin_amdgcn_s_setprio(0);
    float p[4][4];
    float mx = -1e30f;
    int dmin = kt * 64 - q0 - 127, dmax = kt * 64 + 63 - q0;
    bool far = (dmin >= 91) || (dmax <= -91);
    float cb = far ? ((dmin >= 91) ? bR : bL) : 0.f;
    if (far) {
#pragma unroll
      for (int t = 0; t < 4; ++t)
#pragma unroll
        for (int r = 0; r < 4; ++r) {
          float sv = sacc[t][r];
          p[t][r] = sv;
          mx = fmaxf(mx, sv);
        }
    } else {
      int jb = kt * 64 + lh * 4 + 127 - (w * 16 + lr);
#pragma unroll
      for (int t = 0; t < 4; ++t)
#pragma unroll
        for (int r = 0; r < 4; ++r) {
          float sv = sacc[t][r] + bias_s[jb + t * 16 + r];
          p[t][r] = sv;
          mx = fmaxf(mx, sv);
        }
    }
    float me = m_run - cb;
    if (!__all(mx <= me + 11.5f)) {
      mx = fmaxf(mx, __shfl_xor(mx, 16));
      mx = fmaxf(mx, __shfl_xor(mx, 32));
      float men = fmaxf(me, mx);
      float sc = fast_exp2(me - men);
      m_run = men + cb;
      me = men;
      l_run *= sc;
#pragma unroll
      for (int r = 0; r < 4; ++r) {
        float scr = __shfl(sc, lh * 4 + r);
#pragma unroll
        for (int ni = 0; ni < 4; ++ni) oacc[ni][r] *= scr;
      }
    }
    float rs = 0.f;
#pragma unroll
    for (int t = 0; t < 4; ++t)
#pragma unroll
      for (int r = 0; r < 4; ++r) {
        float pv = fast_exp2(p[t][r] - me);
        p[t][r] = pv;
        rs += pv;
      }
    l_run += rs;
    uint32_t pk[4][2];
#pragma unroll
    for (int t = 0; t < 4; ++t) {
      asm("v_cvt_pk_bf16_f32 %0, %1, %2" : "=v"(pk[t][0]) : "v"(p[t][0]), "v"(p[t][1]));
      asm("v_cvt_pk_bf16_f32 %0, %1, %2" : "=v"(pk[t][1]) : "v"(p[t][2]), "v"(p[t][3]));
    }
    u32x4 A0 = {pk[0][0], pk[0][1], pk[1][0], pk[1][1]};
    u32x4 A1 = {pk[2][0], pk[2][1], pk[3][0], pk[3][1]};
    bf16x8 pa0 = __builtin_bit_cast(bf16x8, A0);
    bf16x8 pa1 = __builtin_bit_cast(bf16x8, A1);
    const char* vbr = (const char*)&Vs[buf][0];
    __builtin_amdgcn_s_setprio(1);
#pragma unroll
    for (int ni = 0; ni < 4; ++ni) {
      int vrow = ni * 16 + lr;
      bf16x8 v0 = *(const bf16x8*)(vbr + vrow * 128 + ((lh * 16) ^ swz(vrow)));
      bf16x8 v1 = *(const bf16x8*)(vbr + vrow * 128 + ((64 + lh * 16) ^ swz(vrow)));
      oacc[ni] = __builtin_amdgcn_mfma_f32_16x16x32_bf16(pa0, v0, oacc[ni], 0, 0, 0);
      oacc[ni] = __builtin_amdgcn_mfma_f32_16x16x32_bf16(pa1, v1, oacc[ni], 0, 0, 0);
    }
    __builtin_amdgcn_s_setprio(0);
  };

  // pipeline: pair 0 staged, full drain once; then counted vmcnt keeps the
  // next pair's 4 global_load_lds in flight across both raw barriers.
  stageKV(0, 0);
  stageKV(1, 1);
  __syncthreads();
  for (int kp = 0; kp < 16; ++kp) {
    int rb_ = (kp & 1) * 2;
    if (kp < 15) {
      stageKV(2 * kp + 2, rb_ ^ 2);
      stageKV(2 * kp + 3, (rb_ ^ 2) + 1);
      asm volatile("s_waitcnt vmcnt(4)" ::: "memory");  // pair kp landed; pair kp+1 in flight
    } else {
      asm volatile("s_waitcnt vmcnt(0)" ::: "memory");
    }
    asm volatile("s_barrier" ::: "memory");
    compute(2 * kp, rb_);
    compute(2 * kp + 1, rb_ + 1);
    asm volatile("s_barrier" ::: "memory");             // protect buffer overwrite next iter
  }

  l_run += __shfl_xor(l_run, 16);
  l_run += __shfl_xor(l_run, 32);

#pragma unroll
  for (int r = 0; r < 4; ++r) {
    float linv = 1.0f / __shfl(l_run, lh * 4 + r);
    int s = q0 + w * 16 + lh * 4 + r;
#pragma unroll
    for (int ni = 0; ni < 4; ++ni) {
      int dh = ni * 16 + lr;
      ao[((size_t)(b * 2048 + s)) * 512 + h * 64 + dh] = (__bf16)(oacc[ni][r] * linv);
    }
  }
}

extern "C" void kernel_launch(void* const* d_in, const int* in_sizes, int n_in,
                              void* d_out, int out_size, void* d_ws, size_t ws_size,
                              hipStream_t stream) {
  (void)in_sizes; (void)n_in; (void)out_size; (void)ws_size;
  const float* hs = (const float*)d_in[0];
  const float* Wq = (const float*)d_in[1];
  const float* Wk = (const float*)d_in[2];
  const float* Wv = (const float*)d_in[3];
  const float* Wo = (const float*)d_in[4];
  const float* rb = (const float*)d_in[5];
  char* ws = (char*)d_ws;
  __bf16* hs2    = (__bf16*)(ws + OFF_HS2);
  __bf16* wqkv2  = (__bf16*)(ws + OFF_WQKV2);
  __bf16* wo_t   = (__bf16*)(ws + OFF_WO);
  __bf16* qhb    = (__bf16*)(ws + OFF_QH);
  __bf16* qlb    = (__bf16*)(ws + OFF_QL);
  __bf16* kb     = (__bf16*)(ws + OFF_K);
  __bf16* vtb    = (__bf16*)(ws + OFF_VT);
  __bf16* aob    = (__bf16*)(ws + OFF_AO);
  float*  bias   = (float*)(ws + OFF_BIAS);

  k_prep<<<dim3(8, 8, 36), 256, 0, stream>>>(hs, Wq, Wk, Wv, Wo, rb, hs2, wqkv2, wo_t, bias);
  k_gemm<0, 48, 1024, 1536><<<dim3(12, 64), 256, 0, stream>>>(hs2, wqkv2, qhb, qlb, kb, vtb, nullptr);
  k_attn<<<dim3(512), 512, 0, stream>>>(qhb, qlb, kb, vtb, bias, aob);
  k_gemm<1, 16, 512, 512><<<dim3(4, 64), 256, 0, stream>>>(aob, wo_t, nullptr, nullptr, nullptr, nullptr, (float*)d_out);
}